// Round 1
// baseline (296.887 us; speedup 1.0000x reference)
//
#include <hip/hip_runtime.h>
#include <hip/hip_bf16.h>

// ---------------------------------------------------------------------------
// Wide&Deep forward: 5-layer GEMM chain (bf16 MFMA) + wide-sum + domain head.
// B=16384. Layers: 1024->2048->1024->512 (shared) ->512->256 (domain tower).
// ---------------------------------------------------------------------------

typedef __attribute__((ext_vector_type(8))) short short8;
typedef __attribute__((ext_vector_type(4))) float f32x4;

static __device__ __forceinline__ unsigned short f2bf_bits(float x) {
  __hip_bfloat16 h = __float2bfloat16(x);
  return __builtin_bit_cast(unsigned short, h);
}
static __device__ __forceinline__ float bf_bits2f(unsigned short u) {
  __hip_bfloat16 h = __builtin_bit_cast(__hip_bfloat16, u);
  return __bfloat162float(h);
}

static __device__ __forceinline__ void gload16(const void* g, void* l) {
  __builtin_amdgcn_global_load_lds(
      (const __attribute__((address_space(1))) void*)g,
      (__attribute__((address_space(3))) void*)l, 16, 0, 0);
}

// ---------------------------------------------------------------------------
// Transpose-convert: W [K][N] f32  ->  Wt [N][K] bf16   (B^T layout for MFMA)
// grid = (N/64, K/64), block = 256
// ---------------------------------------------------------------------------
__global__ void transpose_convert(const float* __restrict__ W,
                                  __hip_bfloat16* __restrict__ Wt,
                                  int K, int N) {
  __shared__ float tile[64][65];  // +1 pad: conflict-free transposed reads
  const int k0 = blockIdx.y * 64;
  const int n0 = blockIdx.x * 64;
  const int t  = threadIdx.x;
  const int tn = t & 63;
  const int t4 = t >> 6;  // 0..3
#pragma unroll
  for (int p = 0; p < 16; ++p) {
    int kl = p * 4 + t4;
    tile[kl][tn] = W[(size_t)(k0 + kl) * N + (n0 + tn)];
  }
  __syncthreads();
#pragma unroll
  for (int p = 0; p < 16; ++p) {
    int nl = p * 4 + t4;
    int kl = tn;
    Wt[(size_t)(n0 + nl) * K + (k0 + kl)] =
        __float2bfloat16(tile[kl][nl]);
  }
}

// ---------------------------------------------------------------------------
// f32 -> bf16 bulk convert (8 elements/thread, 16B stores)
// ---------------------------------------------------------------------------
__global__ void f32_to_bf16(const float* __restrict__ in,
                            unsigned short* __restrict__ out, int n8) {
  int i = blockIdx.x * blockDim.x + threadIdx.x;
  if (i >= n8) return;
  const f32x4* p = (const f32x4*)in + (size_t)i * 2;
  f32x4 a = p[0], b = p[1];
  short8 o;
  o[0] = (short)f2bf_bits(a[0]); o[1] = (short)f2bf_bits(a[1]);
  o[2] = (short)f2bf_bits(a[2]); o[3] = (short)f2bf_bits(a[3]);
  o[4] = (short)f2bf_bits(b[0]); o[5] = (short)f2bf_bits(b[1]);
  o[6] = (short)f2bf_bits(b[2]); o[7] = (short)f2bf_bits(b[3]);
  *(short8*)(out + (size_t)i * 8) = o;
}

// ---------------------------------------------------------------------------
// GEMM: C[M,N] = relu(A[M,K] @ W[K,N] + bias), A bf16 row-major,
// Bt = W^T bf16 [N][K]. Writes bf16 Cb always; fp32 Cf if non-null.
// m97 structure: 128x128 tile, BK=64, global_load_lds(16B), 4 waves 2x2,
// 16x16x32 bf16 MFMA, 4x4 frags/wave.
// grid = (N/128, M/128), block = 256.
// ---------------------------------------------------------------------------
__global__ __launch_bounds__(256, 2) void gemm_bt(
    const __hip_bfloat16* __restrict__ A,
    const __hip_bfloat16* __restrict__ Bt,
    const float* __restrict__ bias,
    __hip_bfloat16* __restrict__ Cb,
    float* __restrict__ Cf,
    int N, int K) {
  __shared__ char lds[32768];  // A tile [128][64] bf16 @0, B tile @16384

  const int tid  = threadIdx.x;
  const int lane = tid & 63;
  const int wid  = tid >> 6;
  const int wm   = wid >> 1;   // 0..1
  const int wn   = wid & 1;    // 0..1
  const int bm   = blockIdx.y * 128;
  const int bn   = blockIdx.x * 128;

  f32x4 acc[4][4] = {};

  // staging: thread t, pass p loads 16B (8 bf16) of row (p*32 + t/8),
  // k-chunk (t%8)*8 ; LDS linear byte = p*4096 + t*16  (row-major [128][64])
  const int srow = tid >> 3;          // + p*32
  const int sk   = (tid & 7) * 8;
  const int kTiles = K >> 6;

  for (int kt = 0; kt < kTiles; ++kt) {
    __syncthreads();  // previous tile's reads done
    const __hip_bfloat16* ga = A  + (size_t)(bm + srow) * K + kt * 64 + sk;
    const __hip_bfloat16* gb = Bt + (size_t)(bn + srow) * K + kt * 64 + sk;
#pragma unroll
    for (int p = 0; p < 4; ++p) {
      gload16(ga + (size_t)(p * 32) * K, &lds[p * 4096 + wid * 1024]);
      gload16(gb + (size_t)(p * 32) * K, &lds[16384 + p * 4096 + wid * 1024]);
    }
    __syncthreads();  // drains vmcnt (compiler-inserted) -> tiles visible

#pragma unroll
    for (int kk = 0; kk < 2; ++kk) {
      short8 avec[4], bvec[4];
#pragma unroll
      for (int i = 0; i < 4; ++i) {
        int row = wm * 64 + i * 16 + (lane & 15);
        avec[i] = *(const short8*)&lds[row * 128 + kk * 64 + (lane >> 4) * 16];
      }
#pragma unroll
      for (int j = 0; j < 4; ++j) {
        int row = wn * 64 + j * 16 + (lane & 15);
        bvec[j] = *(const short8*)&lds[16384 + row * 128 + kk * 64 + (lane >> 4) * 16];
      }
#pragma unroll
      for (int i = 0; i < 4; ++i)
#pragma unroll
        for (int j = 0; j < 4; ++j)
          acc[i][j] = __builtin_amdgcn_mfma_f32_16x16x32_bf16(
              avec[i], bvec[j], acc[i][j], 0, 0, 0);
    }
  }

  // epilogue: bias + relu; C/D layout: col = lane&15, row = (lane>>4)*4 + r
  float biasv[4];
#pragma unroll
  for (int j = 0; j < 4; ++j)
    biasv[j] = bias[bn + wn * 64 + j * 16 + (lane & 15)];

#pragma unroll
  for (int i = 0; i < 4; ++i) {
    int row0 = bm + wm * 64 + i * 16 + (lane >> 4) * 4;
#pragma unroll
    for (int j = 0; j < 4; ++j) {
      int col = bn + wn * 64 + j * 16 + (lane & 15);
#pragma unroll
      for (int r = 0; r < 4; ++r) {
        float v = acc[i][j][r] + biasv[j];
        v = v > 0.f ? v : 0.f;
        size_t idx = (size_t)(row0 + r) * N + col;
        Cb[idx] = __float2bfloat16(v);
        if (Cf) Cf[idx] = v;
      }
    }
  }
}

// ---------------------------------------------------------------------------
// Head: out[r] = sigmoid( sum(wide[r,:]) + sum(D[r,:]*Wh[dom[r],:]) + bh[dom[r]] )
// one wave per row, 4 rows per block
// ---------------------------------------------------------------------------
__global__ __launch_bounds__(256) void head_kernel(
    const float* __restrict__ wide,
    const __hip_bfloat16* __restrict__ D,
    const int* __restrict__ dom,
    const float* __restrict__ Wh,
    const float* __restrict__ bh,
    float* __restrict__ out, int B) {
  const int wid  = threadIdx.x >> 6;
  const int lane = threadIdx.x & 63;
  const int row  = blockIdx.x * 4 + wid;
  if (row >= B) return;
  const int dm = dom[row];

  f32x4 wv = ((const f32x4*)(wide + (size_t)row * 256))[lane];
  float tot = wv[0] + wv[1] + wv[2] + wv[3];

  const unsigned short* drow = (const unsigned short*)(D + (size_t)row * 256);
  ushort4 dv = ((const ushort4*)drow)[lane];
  f32x4 hv = ((const f32x4*)(Wh + (size_t)dm * 256))[lane];
  tot += bf_bits2f(dv.x) * hv[0] + bf_bits2f(dv.y) * hv[1] +
         bf_bits2f(dv.z) * hv[2] + bf_bits2f(dv.w) * hv[3];

#pragma unroll
  for (int off = 32; off > 0; off >>= 1) tot += __shfl_xor(tot, off);

  if (lane == 0) {
    float x = tot + bh[dm];
    out[row] = 1.f / (1.f + __expf(-x));
  }
}

// ---------------------------------------------------------------------------
extern "C" void kernel_launch(void* const* d_in, const int* in_sizes, int n_in,
                              void* d_out, int out_size, void* d_ws, size_t ws_size,
                              hipStream_t stream) {
  const float* wide = (const float*)d_in[0];
  const float* deep = (const float*)d_in[1];
  const int*   dom  = (const int*)d_in[2];
  const float* W1  = (const float*)d_in[3];
  const float* b1  = (const float*)d_in[4];
  const float* W2  = (const float*)d_in[5];
  const float* b2  = (const float*)d_in[6];
  const float* W3  = (const float*)d_in[7];
  const float* b3  = (const float*)d_in[8];
  const float* Wd1 = (const float*)d_in[9];
  const float* bd1 = (const float*)d_in[10];
  const float* Wd2 = (const float*)d_in[11];
  const float* bd2 = (const float*)d_in[12];
  const float* Wh  = (const float*)d_in[13];
  const float* bh  = (const float*)d_in[14];
  float* out = (float*)d_out;

  const int B = 16384;
  char* ws = (char*)d_ws;
  // buf0: 32MB (A0 / H2 / T1), buf1: 64MB (H1 / S / D), then bf16 weights
  __hip_bfloat16* buf0 = (__hip_bfloat16*)ws;
  __hip_bfloat16* buf1 = (__hip_bfloat16*)(ws + 33554432ull);
  __hip_bfloat16* W1t  = (__hip_bfloat16*)(ws + 100663296ull);
  __hip_bfloat16* W2t  = W1t + 2048 * 1024;
  __hip_bfloat16* W3t  = W2t + 1024 * 2048;
  __hip_bfloat16* Wd1t = W3t + 512 * 1024;
  __hip_bfloat16* Wd2t = Wd1t + 512 * 512;

  // weights -> bf16 transposed [N][K]
  transpose_convert<<<dim3(2048 / 64, 1024 / 64), 256, 0, stream>>>(W1, W1t, 1024, 2048);
  transpose_convert<<<dim3(1024 / 64, 2048 / 64), 256, 0, stream>>>(W2, W2t, 2048, 1024);
  transpose_convert<<<dim3(512 / 64, 1024 / 64), 256, 0, stream>>>(W3, W3t, 1024, 512);
  transpose_convert<<<dim3(512 / 64, 512 / 64), 256, 0, stream>>>(Wd1, Wd1t, 512, 512);
  transpose_convert<<<dim3(256 / 64, 512 / 64), 256, 0, stream>>>(Wd2, Wd2t, 512, 256);

  // deep -> bf16
  {
    int n8 = B * 1024 / 8;
    f32_to_bf16<<<(n8 + 255) / 256, 256, 0, stream>>>(deep, (unsigned short*)buf0, n8);
  }

  float* shared_out = out + B;                 // [B,512]
  float* d_out_f    = out + B + (size_t)B * 512;  // [B,256]

  // L1: [B,1024] x [1024,2048] -> H1 (buf1)
  gemm_bt<<<dim3(2048 / 128, B / 128), 256, 0, stream>>>(buf0, W1t, b1, buf1, nullptr, 2048, 1024);
  // L2: -> H2 (buf0)
  gemm_bt<<<dim3(1024 / 128, B / 128), 256, 0, stream>>>(buf1, W2t, b2, buf0, nullptr, 1024, 2048);
  // L3: -> shared S (buf1 bf16 + fp32 out)
  gemm_bt<<<dim3(512 / 128, B / 128), 256, 0, stream>>>(buf0, W3t, b3, buf1, shared_out, 512, 1024);
  // L4: -> T1 (buf0)
  gemm_bt<<<dim3(512 / 128, B / 128), 256, 0, stream>>>(buf1, Wd1t, bd1, buf0, nullptr, 512, 512);
  // L5: -> D (buf1 bf16 + fp32 out)
  gemm_bt<<<dim3(256 / 128, B / 128), 256, 0, stream>>>(buf0, Wd2t, bd2, buf1, d_out_f, 256, 512);

  // head
  head_kernel<<<B / 4, 256, 0, stream>>>(wide, buf1, dom, Wh, bh, out, B);
}

// Round 2
// 241.220 us; speedup vs baseline: 1.2308x; 1.2308x over previous
//
#include <hip/hip_runtime.h>
#include <hip/hip_bf16.h>

// ---------------------------------------------------------------------------
// Wide&Deep forward: 5-layer GEMM chain (bf16 MFMA) + wide-sum + domain head.
// L1/L2 (M=16384, N=2048/1024): 256x256 8-phase pipelined kernel (T1-T5).
// L3-L5: m97-structure 128x128 kernel.
// ---------------------------------------------------------------------------

typedef __attribute__((ext_vector_type(8))) short short8;
typedef __attribute__((ext_vector_type(4))) float f32x4;

static __device__ __forceinline__ unsigned short f2bf_bits(float x) {
  __hip_bfloat16 h = __float2bfloat16(x);
  return __builtin_bit_cast(unsigned short, h);
}
static __device__ __forceinline__ float bf_bits2f(unsigned short u) {
  __hip_bfloat16 h = __builtin_bit_cast(__hip_bfloat16, u);
  return __bfloat162float(h);
}

static __device__ __forceinline__ void gload16(const void* g, void* l) {
  __builtin_amdgcn_global_load_lds(
      (const __attribute__((address_space(1))) void*)g,
      (__attribute__((address_space(3))) void*)l, 16, 0, 0);
}

#define MFMA16(a, b, c) __builtin_amdgcn_mfma_f32_16x16x32_bf16((a), (b), (c), 0, 0, 0)

// ---------------------------------------------------------------------------
// Transpose-convert: W [K][N] f32 -> Wt [N][K] bf16
// ---------------------------------------------------------------------------
__global__ void transpose_convert(const float* __restrict__ W,
                                  __hip_bfloat16* __restrict__ Wt,
                                  int K, int N) {
  __shared__ float tile[64][65];
  const int k0 = blockIdx.y * 64;
  const int n0 = blockIdx.x * 64;
  const int t  = threadIdx.x;
  const int tn = t & 63;
  const int t4 = t >> 6;
#pragma unroll
  for (int p = 0; p < 16; ++p) {
    int kl = p * 4 + t4;
    tile[kl][tn] = W[(size_t)(k0 + kl) * N + (n0 + tn)];
  }
  __syncthreads();
#pragma unroll
  for (int p = 0; p < 16; ++p) {
    int nl = p * 4 + t4;
    Wt[(size_t)(n0 + nl) * K + (k0 + tn)] = __float2bfloat16(tile[tn][nl]);
  }
}

// ---------------------------------------------------------------------------
// f32 -> bf16 bulk convert
// ---------------------------------------------------------------------------
__global__ void f32_to_bf16(const float* __restrict__ in,
                            unsigned short* __restrict__ out, int n8) {
  int i = blockIdx.x * blockDim.x + threadIdx.x;
  if (i >= n8) return;
  const f32x4* p = (const f32x4*)in + (size_t)i * 2;
  f32x4 a = p[0], b = p[1];
  short8 o;
  o[0] = (short)f2bf_bits(a[0]); o[1] = (short)f2bf_bits(a[1]);
  o[2] = (short)f2bf_bits(a[2]); o[3] = (short)f2bf_bits(a[3]);
  o[4] = (short)f2bf_bits(b[0]); o[5] = (short)f2bf_bits(b[1]);
  o[6] = (short)f2bf_bits(b[2]); o[7] = (short)f2bf_bits(b[3]);
  *(short8*)(out + (size_t)i * 8) = o;
}

// ---------------------------------------------------------------------------
// 256x256 8-phase GEMM (BK=64, 8 waves 2x4, dbuf LDS 128KB, swizzled reads).
// C = relu(A @ Bt^T + bias). A [M][K] bf16, Bt [N][K] bf16. N%256==0, K%64==0.
// Issue schedule (tile x): B0@p3(x-2) A0@p4(x-2) B1@p1(x-1) A1@p2(x-1).
// ds_read phases {12,4,8,0}; every overwrite >=2 barriers after last read.
// vmcnt(4) once per tile (tail: vmcnt(0)).
// ---------------------------------------------------------------------------
__global__ __launch_bounds__(512, 2) void gemm_8p(
    const __hip_bfloat16* __restrict__ A,
    const __hip_bfloat16* __restrict__ Bt,
    const float* __restrict__ bias,
    __hip_bfloat16* __restrict__ Cb,
    float* __restrict__ Cf,
    int N, int K, int nbx) {
  __shared__ char lds[131072];  // buf(t&1)*65536 : A tile 32KB, B tile @+32768

  const int tid  = threadIdx.x;
  const int lane = tid & 63;
  const int wid  = tid >> 6;
  const int wm   = wid >> 2;   // 0..1 -> rows wm*128..+127
  const int wn   = wid & 3;    // 0..3 -> cols wn*64..+63

  // T1: bijective XCD swizzle (gridDim.x % 8 == 0)
  const int nwg = gridDim.x;
  const int cpx = nwg >> 3;
  const int id  = blockIdx.x;
  const int swz = (id & 7) * cpx + (id >> 3);
  const int bm  = (swz / nbx) * 256;
  const int bn  = (swz % nbx) * 256;

  const int ln15 = lane & 15;
  const int ln7  = lane & 7;
  const int cswz = (((lane >> 4) ^ ln7) << 4);  // swizzled chunk byte @ kk=0

  const int nt = K >> 6;

  // stage one half-tile (2 x global_load_lds per thread), pre-swizzled source
  auto stage = [&](int kt, int half, int isB) {
    const __hip_bfloat16* G = isB ? Bt : A;
    const int blk0 = isB ? bn : bm;
    char* base = lds + ((kt & 1) * 65536) + (isB ? 32768 : 0) + half * 16384;
#pragma unroll
    for (int q = 0; q < 2; ++q) {
      int rl  = half * 128 + q * 64 + (tid >> 3);
      int swc = (tid & 7) ^ ((tid >> 3) & 7);
      gload16(G + (size_t)(blk0 + rl) * K + kt * 64 + swc * 8,
              base + q * 8192 + wid * 1024);
    }
  };

  f32x4 acc[8][4] = {};

  // prologue: tile0 all halves + tile1 {B0, A0}
  stage(0, 0, 1); stage(0, 0, 0); stage(0, 1, 1); stage(0, 1, 0);
  if (nt > 1) {
    stage(1, 0, 1); stage(1, 0, 0);
    asm volatile("s_waitcnt vmcnt(4)" ::: "memory");
  } else {
    asm volatile("s_waitcnt vmcnt(0)" ::: "memory");
  }
  __builtin_amdgcn_s_barrier();

  for (int t = 0; t < nt; ++t) {
    const char* ldsA = lds + (t & 1) * 65536;
    const char* ldsB = ldsA + 32768;
    auto afrag = [&](int mi, int kk) -> short8 {
      return *(const short8*)(ldsA + (wm * 128 + mi * 16 + ln15) * 128 +
                              (cswz ^ (kk << 6)));
    };
    auto bfrag = [&](int nj, int kk) -> short8 {
      return *(const short8*)(ldsB + (wn * 64 + nj * 16 + ln15) * 128 +
                              (cswz ^ (kk << 6)));
    };

    short8 a_[4][2], b0_[2][2], b1_[2][2];

    // ---- phase 1: Q0 operands (12 ds_read), stage (t+1).B1 ----
#pragma unroll
    for (int mi = 0; mi < 4; ++mi) { a_[mi][0] = afrag(mi, 0); a_[mi][1] = afrag(mi, 1); }
#pragma unroll
    for (int nj = 0; nj < 2; ++nj) { b0_[nj][0] = bfrag(nj, 0); b0_[nj][1] = bfrag(nj, 1); }
    if (t + 1 < nt) stage(t + 1, 1, 1);
    asm volatile("s_waitcnt lgkmcnt(8)" ::: "memory");
    __builtin_amdgcn_s_barrier();
    asm volatile("s_waitcnt lgkmcnt(0)" ::: "memory");
    __builtin_amdgcn_sched_barrier(0);
    __builtin_amdgcn_s_setprio(1);
#pragma unroll
    for (int mi = 0; mi < 4; ++mi)
#pragma unroll
      for (int nj = 0; nj < 2; ++nj)
#pragma unroll
        for (int kk = 0; kk < 2; ++kk)
          acc[mi][nj] = MFMA16(a_[mi][kk], b0_[nj][kk], acc[mi][nj]);
    __builtin_amdgcn_s_setprio(0);
    __builtin_amdgcn_s_barrier();

    // ---- phase 2: Q1 B-operands (4 ds_read), stage (t+1).A1 ----
#pragma unroll
    for (int nj = 0; nj < 2; ++nj) { b1_[nj][0] = bfrag(nj + 2, 0); b1_[nj][1] = bfrag(nj + 2, 1); }
    if (t + 1 < nt) stage(t + 1, 1, 0);
    __builtin_amdgcn_s_barrier();
    asm volatile("s_waitcnt lgkmcnt(0)" ::: "memory");
    __builtin_amdgcn_sched_barrier(0);
    __builtin_amdgcn_s_setprio(1);
#pragma unroll
    for (int mi = 0; mi < 4; ++mi)
#pragma unroll
      for (int nj = 0; nj < 2; ++nj)
#pragma unroll
        for (int kk = 0; kk < 2; ++kk)
          acc[mi][nj + 2] = MFMA16(a_[mi][kk], b1_[nj][kk], acc[mi][nj + 2]);
    __builtin_amdgcn_s_setprio(0);
    __builtin_amdgcn_s_barrier();

    // ---- phase 3: Q2 A-operands (8 ds_read), stage (t+2).B0 ----
#pragma unroll
    for (int mi = 0; mi < 4; ++mi) { a_[mi][0] = afrag(mi + 4, 0); a_[mi][1] = afrag(mi + 4, 1); }
    if (t + 2 < nt) stage(t + 2, 0, 1);
    __builtin_amdgcn_s_barrier();
    asm volatile("s_waitcnt lgkmcnt(0)" ::: "memory");
    __builtin_amdgcn_sched_barrier(0);
    __builtin_amdgcn_s_setprio(1);
#pragma unroll
    for (int mi = 0; mi < 4; ++mi)
#pragma unroll
      for (int nj = 0; nj < 2; ++nj)
#pragma unroll
        for (int kk = 0; kk < 2; ++kk)
          acc[mi + 4][nj] = MFMA16(a_[mi][kk], b0_[nj][kk], acc[mi + 4][nj]);
    __builtin_amdgcn_s_setprio(0);
    __builtin_amdgcn_s_barrier();

    // ---- phase 4: Q3 (0 ds_read), stage (t+2).A0, tile-end vmcnt ----
    if (t + 2 < nt) stage(t + 2, 0, 0);
    __builtin_amdgcn_s_barrier();
    __builtin_amdgcn_s_setprio(1);
#pragma unroll
    for (int mi = 0; mi < 4; ++mi)
#pragma unroll
      for (int nj = 0; nj < 2; ++nj)
#pragma unroll
        for (int kk = 0; kk < 2; ++kk)
          acc[mi + 4][nj + 2] = MFMA16(a_[mi][kk], b1_[nj][kk], acc[mi + 4][nj + 2]);
    __builtin_amdgcn_s_setprio(0);
    if (t + 2 < nt) asm volatile("s_waitcnt vmcnt(4)" ::: "memory");
    else            asm volatile("s_waitcnt vmcnt(0)" ::: "memory");
    __builtin_amdgcn_sched_barrier(0);
    __builtin_amdgcn_s_barrier();
  }

  // epilogue: bias + relu; C/D: col = lane&15, row = (lane>>4)*4 + r
  float biasv[4];
#pragma unroll
  for (int nj = 0; nj < 4; ++nj)
    biasv[nj] = bias[bn + wn * 64 + nj * 16 + ln15];

#pragma unroll
  for (int mi = 0; mi < 8; ++mi) {
    int row0 = bm + wm * 128 + mi * 16 + (lane >> 4) * 4;
#pragma unroll
    for (int nj = 0; nj < 4; ++nj) {
      int col = bn + wn * 64 + nj * 16 + ln15;
#pragma unroll
      for (int r = 0; r < 4; ++r) {
        float v = acc[mi][nj][r] + biasv[nj];
        v = v > 0.f ? v : 0.f;
        size_t idx = (size_t)(row0 + r) * N + col;
        Cb[idx] = __float2bfloat16(v);
        if (Cf) Cf[idx] = v;
      }
    }
  }
}

// ---------------------------------------------------------------------------
// m97-structure 128x128 GEMM for the small-N layers (L3-L5).
// ---------------------------------------------------------------------------
__global__ __launch_bounds__(256, 2) void gemm_bt(
    const __hip_bfloat16* __restrict__ A,
    const __hip_bfloat16* __restrict__ Bt,
    const float* __restrict__ bias,
    __hip_bfloat16* __restrict__ Cb,
    float* __restrict__ Cf,
    int N, int K) {
  __shared__ char lds[32768];

  const int tid  = threadIdx.x;
  const int lane = tid & 63;
  const int wid  = tid >> 6;
  const int wm   = wid >> 1;
  const int wn   = wid & 1;
  const int bm   = blockIdx.y * 128;
  const int bn   = blockIdx.x * 128;

  f32x4 acc[4][4] = {};

  const int srow = tid >> 3;
  const int sk   = (tid & 7) * 8;
  const int kTiles = K >> 6;

  for (int kt = 0; kt < kTiles; ++kt) {
    __syncthreads();
    const __hip_bfloat16* ga = A  + (size_t)(bm + srow) * K + kt * 64 + sk;
    const __hip_bfloat16* gb = Bt + (size_t)(bn + srow) * K + kt * 64 + sk;
#pragma unroll
    for (int p = 0; p < 4; ++p) {
      gload16(ga + (size_t)(p * 32) * K, &lds[p * 4096 + wid * 1024]);
      gload16(gb + (size_t)(p * 32) * K, &lds[16384 + p * 4096 + wid * 1024]);
    }
    __syncthreads();

#pragma unroll
    for (int kk = 0; kk < 2; ++kk) {
      short8 avec[4], bvec[4];
#pragma unroll
      for (int i = 0; i < 4; ++i) {
        int row = wm * 64 + i * 16 + (lane & 15);
        avec[i] = *(const short8*)&lds[row * 128 + kk * 64 + (lane >> 4) * 16];
      }
#pragma unroll
      for (int j = 0; j < 4; ++j) {
        int row = wn * 64 + j * 16 + (lane & 15);
        bvec[j] = *(const short8*)&lds[16384 + row * 128 + kk * 64 + (lane >> 4) * 16];
      }
#pragma unroll
      for (int i = 0; i < 4; ++i)
#pragma unroll
        for (int j = 0; j < 4; ++j)
          acc[i][j] = MFMA16(avec[i], bvec[j], acc[i][j]);
    }
  }

  float biasv[4];
#pragma unroll
  for (int j = 0; j < 4; ++j)
    biasv[j] = bias[bn + wn * 64 + j * 16 + (lane & 15)];

#pragma unroll
  for (int i = 0; i < 4; ++i) {
    int row0 = bm + wm * 64 + i * 16 + (lane >> 4) * 4;
#pragma unroll
    for (int j = 0; j < 4; ++j) {
      int col = bn + wn * 64 + j * 16 + (lane & 15);
#pragma unroll
      for (int r = 0; r < 4; ++r) {
        float v = acc[i][j][r] + biasv[j];
        v = v > 0.f ? v : 0.f;
        size_t idx = (size_t)(row0 + r) * N + col;
        Cb[idx] = __float2bfloat16(v);
        if (Cf) Cf[idx] = v;
      }
    }
  }
}

// ---------------------------------------------------------------------------
// Head: out[r] = sigmoid( sum(wide[r,:]) + dot(D[r,:], Wh[dom[r],:]) + bh[dom[r]] )
// ---------------------------------------------------------------------------
__global__ __launch_bounds__(256) void head_kernel(
    const float* __restrict__ wide,
    const __hip_bfloat16* __restrict__ D,
    const int* __restrict__ dom,
    const float* __restrict__ Wh,
    const float* __restrict__ bh,
    float* __restrict__ out, int B) {
  const int wid  = threadIdx.x >> 6;
  const int lane = threadIdx.x & 63;
  const int row  = blockIdx.x * 4 + wid;
  if (row >= B) return;
  const int dm = dom[row];

  f32x4 wv = ((const f32x4*)(wide + (size_t)row * 256))[lane];
  float tot = wv[0] + wv[1] + wv[2] + wv[3];

  const unsigned short* drow = (const unsigned short*)(D + (size_t)row * 256);
  ushort4 dv = ((const ushort4*)drow)[lane];
  f32x4 hv = ((const f32x4*)(Wh + (size_t)dm * 256))[lane];
  tot += bf_bits2f(dv.x) * hv[0] + bf_bits2f(dv.y) * hv[1] +
         bf_bits2f(dv.z) * hv[2] + bf_bits2f(dv.w) * hv[3];

#pragma unroll
  for (int off = 32; off > 0; off >>= 1) tot += __shfl_xor(tot, off);

  if (lane == 0) {
    float x = tot + bh[dm];
    out[row] = 1.f / (1.f + __expf(-x));
  }
}

// ---------------------------------------------------------------------------
extern "C" void kernel_launch(void* const* d_in, const int* in_sizes, int n_in,
                              void* d_out, int out_size, void* d_ws, size_t ws_size,
                              hipStream_t stream) {
  const float* wide = (const float*)d_in[0];
  const float* deep = (const float*)d_in[1];
  const int*   dom  = (const int*)d_in[2];
  const float* W1  = (const float*)d_in[3];
  const float* b1  = (const float*)d_in[4];
  const float* W2  = (const float*)d_in[5];
  const float* b2  = (const float*)d_in[6];
  const float* W3  = (const float*)d_in[7];
  const float* b3  = (const float*)d_in[8];
  const float* Wd1 = (const float*)d_in[9];
  const float* bd1 = (const float*)d_in[10];
  const float* Wd2 = (const float*)d_in[11];
  const float* bd2 = (const float*)d_in[12];
  const float* Wh  = (const float*)d_in[13];
  const float* bh  = (const float*)d_in[14];
  float* out = (float*)d_out;

  const int B = 16384;
  char* ws = (char*)d_ws;
  __hip_bfloat16* buf0 = (__hip_bfloat16*)ws;
  __hip_bfloat16* buf1 = (__hip_bfloat16*)(ws + 33554432ull);
  __hip_bfloat16* W1t  = (__hip_bfloat16*)(ws + 100663296ull);
  __hip_bfloat16* W2t  = W1t + 2048 * 1024;
  __hip_bfloat16* W3t  = W2t + 1024 * 2048;
  __hip_bfloat16* Wd1t = W3t + 512 * 1024;
  __hip_bfloat16* Wd2t = Wd1t + 512 * 512;

  transpose_convert<<<dim3(2048 / 64, 1024 / 64), 256, 0, stream>>>(W1, W1t, 1024, 2048);
  transpose_convert<<<dim3(1024 / 64, 2048 / 64), 256, 0, stream>>>(W2, W2t, 2048, 1024);
  transpose_convert<<<dim3(512 / 64, 1024 / 64), 256, 0, stream>>>(W3, W3t, 1024, 512);
  transpose_convert<<<dim3(512 / 64, 512 / 64), 256, 0, stream>>>(Wd1, Wd1t, 512, 512);
  transpose_convert<<<dim3(256 / 64, 512 / 64), 256, 0, stream>>>(Wd2, Wd2t, 512, 256);

  {
    int n8 = B * 1024 / 8;
    f32_to_bf16<<<(n8 + 255) / 256, 256, 0, stream>>>(deep, (unsigned short*)buf0, n8);
  }

  float* shared_out = out + B;
  float* d_out_f    = out + B + (size_t)B * 512;

  // L1: [B,1024] x [1024,2048] -> H1 (buf1)   [8-phase 256^2, 512 blocks]
  gemm_8p<<<dim3((2048 / 256) * (B / 256)), 512, 0, stream>>>(
      buf0, W1t, b1, buf1, nullptr, 2048, 1024, 2048 / 256);
  // L2: [B,2048] x [2048,1024] -> H2 (buf0)   [8-phase 256^2, 256 blocks]
  gemm_8p<<<dim3((1024 / 256) * (B / 256)), 512, 0, stream>>>(
      buf1, W2t, b2, buf0, nullptr, 1024, 2048, 1024 / 256);
  // L3: -> shared S (buf1 bf16 + fp32 out)
  gemm_bt<<<dim3(512 / 128, B / 128), 256, 0, stream>>>(buf0, W3t, b3, buf1, shared_out, 512, 1024);
  // L4: -> T1 (buf0)
  gemm_bt<<<dim3(512 / 128, B / 128), 256, 0, stream>>>(buf1, Wd1t, bd1, buf0, nullptr, 512, 512);
  // L5: -> D (buf1 bf16 + fp32 out)
  gemm_bt<<<dim3(256 / 128, B / 128), 256, 0, stream>>>(buf0, Wd2t, bd2, buf1, d_out_f, 256, 512);

  head_kernel<<<B / 4, 256, 0, stream>>>(wide, buf1, dom, Wh, bh, out, B);
}

// Round 3
// 240.505 us; speedup vs baseline: 1.2344x; 1.0030x over previous
//
#include <hip/hip_runtime.h>
#include <hip/hip_bf16.h>

// ---------------------------------------------------------------------------
// Wide&Deep forward: 5-layer GEMM chain (bf16 MFMA) + wide-sum + domain head.
// L1/L2: 256x256 8-phase pipelined kernel, inline-asm ds_read (T1-T5).
// L3-L5: m97-structure 128x128 kernel.
// ---------------------------------------------------------------------------

typedef __attribute__((ext_vector_type(8))) short short8;
typedef __attribute__((ext_vector_type(4))) float f32x4;

static __device__ __forceinline__ unsigned short f2bf_bits(float x) {
  __hip_bfloat16 h = __float2bfloat16(x);
  return __builtin_bit_cast(unsigned short, h);
}
static __device__ __forceinline__ float bf_bits2f(unsigned short u) {
  __hip_bfloat16 h = __builtin_bit_cast(__hip_bfloat16, u);
  return __bfloat162float(h);
}

static __device__ __forceinline__ void gload16(const void* g, void* l) {
  __builtin_amdgcn_global_load_lds(
      (const __attribute__((address_space(1))) void*)g,
      (__attribute__((address_space(3))) void*)l, 16, 0, 0);
}

// 32-bit LDS byte address from a generic pointer into a __shared__ array
static __device__ __forceinline__ unsigned lds_u32(const void* p) {
  return (unsigned)(uintptr_t)(const __attribute__((address_space(3))) void*)p;
}

// compiler-invisible LDS read (no memory dep => no compiler-inserted vmcnt)
static __device__ __forceinline__ short8 dsr(unsigned addr) {
  short8 r;
  asm volatile("ds_read_b128 %0, %1" : "=v"(r) : "v"(addr));
  return r;
}

#define MFMA16(a, b, c) __builtin_amdgcn_mfma_f32_16x16x32_bf16((a), (b), (c), 0, 0, 0)

// ---------------------------------------------------------------------------
// Transpose-convert: W [K][N] f32 -> Wt [N][K] bf16
// ---------------------------------------------------------------------------
__global__ void transpose_convert(const float* __restrict__ W,
                                  __hip_bfloat16* __restrict__ Wt,
                                  int K, int N) {
  __shared__ float tile[64][65];
  const int k0 = blockIdx.y * 64;
  const int n0 = blockIdx.x * 64;
  const int t  = threadIdx.x;
  const int tn = t & 63;
  const int t4 = t >> 6;
#pragma unroll
  for (int p = 0; p < 16; ++p) {
    int kl = p * 4 + t4;
    tile[kl][tn] = W[(size_t)(k0 + kl) * N + (n0 + tn)];
  }
  __syncthreads();
#pragma unroll
  for (int p = 0; p < 16; ++p) {
    int nl = p * 4 + t4;
    Wt[(size_t)(n0 + nl) * K + (k0 + tn)] = __float2bfloat16(tile[tn][nl]);
  }
}

// ---------------------------------------------------------------------------
// f32 -> bf16 bulk convert
// ---------------------------------------------------------------------------
__global__ void f32_to_bf16(const float* __restrict__ in,
                            unsigned short* __restrict__ out, int n8) {
  int i = blockIdx.x * blockDim.x + threadIdx.x;
  if (i >= n8) return;
  const f32x4* p = (const f32x4*)in + (size_t)i * 2;
  f32x4 a = p[0], b = p[1];
  short8 o;
  o[0] = (short)f2bf_bits(a[0]); o[1] = (short)f2bf_bits(a[1]);
  o[2] = (short)f2bf_bits(a[2]); o[3] = (short)f2bf_bits(a[3]);
  o[4] = (short)f2bf_bits(b[0]); o[5] = (short)f2bf_bits(b[1]);
  o[6] = (short)f2bf_bits(b[2]); o[7] = (short)f2bf_bits(b[3]);
  *(short8*)(out + (size_t)i * 8) = o;
}

// ---------------------------------------------------------------------------
// 256x256 8-phase GEMM (BK=64, 8 waves 2x4, dbuf LDS 128KB, swizzled reads).
// C = relu(A @ Bt^T + bias). A [M][K] bf16, Bt [N][K] bf16. N%256==0, K%64==0.
// Stage schedule (tile x consumed at iter x): B0@p3(x-2) A0@p4(x-2)
// B1@p1(x-1) A1@p2(x-1). ds_read phases {12,4,8,0}, all via inline asm
// (invisible to compiler memory model -> our counted vmcnt is the only VMEM
// wait in the loop). vmcnt(4) once per tile (tail: vmcnt(0)).
// WAR safety: every LDS overwrite is issued >=1 barrier after a block-wide
// lgkmcnt(0) drain of all reads touching that region.
// ---------------------------------------------------------------------------
__global__ __launch_bounds__(512, 2) void gemm_8p(
    const __hip_bfloat16* __restrict__ A,
    const __hip_bfloat16* __restrict__ Bt,
    const float* __restrict__ bias,
    __hip_bfloat16* __restrict__ Cb,
    float* __restrict__ Cf,
    int N, int K, int nbx) {
  __shared__ char lds[131072];  // buf(t&1)*65536 : A tile 32KB, B tile @+32768

  const int tid  = threadIdx.x;
  const int lane = tid & 63;
  const int wid  = tid >> 6;
  const int wm   = wid >> 2;   // 0..1 -> rows wm*128..+127
  const int wn   = wid & 3;    // 0..3 -> cols wn*64..+63

  // T1: bijective XCD swizzle (gridDim.x % 8 == 0)
  const int nwg = gridDim.x;
  const int cpx = nwg >> 3;
  const int id  = blockIdx.x;
  const int swz = (id & 7) * cpx + (id >> 3);
  const int bm  = (swz / nbx) * 256;
  const int bn  = (swz % nbx) * 256;

  const int ln15 = lane & 15;
  const unsigned cswz = (unsigned)((((lane >> 4) ^ (lane & 7)) << 4));

  const unsigned lbase = lds_u32(lds);
  const unsigned arow0 = lbase + (unsigned)(wm * 128 + ln15) * 128u + cswz;
  const unsigned brow0 = lbase + 32768u + (unsigned)(wn * 64 + ln15) * 128u + cswz;

  const int nt = K >> 6;

  // stage one half-tile (2 x global_load_lds per thread), pre-swizzled source
  auto stage = [&](int kt, int half, int isB) {
    const __hip_bfloat16* G = isB ? Bt : A;
    const int blk0 = isB ? bn : bm;
    char* base = lds + ((kt & 1) * 65536) + (isB ? 32768 : 0) + half * 16384;
#pragma unroll
    for (int q = 0; q < 2; ++q) {
      int rl  = half * 128 + q * 64 + (tid >> 3);
      int swc = (tid & 7) ^ ((tid >> 3) & 7);
      gload16(G + (size_t)(blk0 + rl) * K + kt * 64 + swc * 8,
              base + q * 8192 + wid * 1024);
    }
  };

  f32x4 acc[8][4] = {};

  // prologue: tile0 all halves + tile1 {B0, A0}
  stage(0, 0, 1); stage(0, 0, 0); stage(0, 1, 1); stage(0, 1, 0);
  if (nt > 1) {
    stage(1, 0, 1); stage(1, 0, 0);
    asm volatile("s_waitcnt vmcnt(4)");
  } else {
    asm volatile("s_waitcnt vmcnt(0)");
  }
  __builtin_amdgcn_s_barrier();

  for (int t = 0; t < nt; ++t) {
    const unsigned po = (unsigned)(t & 1) * 65536u;
    short8 a_[4][2], b0_[2][2], b1_[2][2];

    // ---- phase 1: Q0 operands (12 ds_read), stage (t+1).B1 ----
#pragma unroll
    for (int mi = 0; mi < 4; ++mi) {
      unsigned ad = arow0 + po + (unsigned)(mi * 2048);
      a_[mi][0] = dsr(ad); a_[mi][1] = dsr(ad ^ 64u);
    }
#pragma unroll
    for (int nj = 0; nj < 2; ++nj) {
      unsigned bd = brow0 + po + (unsigned)(nj * 2048);
      b0_[nj][0] = dsr(bd); b0_[nj][1] = dsr(bd ^ 64u);
    }
    if (t + 1 < nt) stage(t + 1, 1, 1);
    asm volatile("s_waitcnt lgkmcnt(8)");
    __builtin_amdgcn_s_barrier();
    asm volatile("s_waitcnt lgkmcnt(0)");
    __builtin_amdgcn_sched_barrier(0);
    __builtin_amdgcn_s_setprio(1);
#pragma unroll
    for (int mi = 0; mi < 4; ++mi)
#pragma unroll
      for (int nj = 0; nj < 2; ++nj)
#pragma unroll
        for (int kk = 0; kk < 2; ++kk)
          acc[mi][nj] = MFMA16(a_[mi][kk], b0_[nj][kk], acc[mi][nj]);
    __builtin_amdgcn_s_setprio(0);
    __builtin_amdgcn_s_barrier();

    // ---- phase 2: Q1 B-operands (4 ds_read), stage (t+1).A1 ----
#pragma unroll
    for (int nj = 0; nj < 2; ++nj) {
      unsigned bd = brow0 + po + (unsigned)((nj + 2) * 2048);
      b1_[nj][0] = dsr(bd); b1_[nj][1] = dsr(bd ^ 64u);
    }
    if (t + 1 < nt) stage(t + 1, 1, 0);
    __builtin_amdgcn_s_barrier();
    asm volatile("s_waitcnt lgkmcnt(0)");
    __builtin_amdgcn_sched_barrier(0);
    __builtin_amdgcn_s_setprio(1);
#pragma unroll
    for (int mi = 0; mi < 4; ++mi)
#pragma unroll
      for (int nj = 0; nj < 2; ++nj)
#pragma unroll
        for (int kk = 0; kk < 2; ++kk)
          acc[mi][nj + 2] = MFMA16(a_[mi][kk], b1_[nj][kk], acc[mi][nj + 2]);
    __builtin_amdgcn_s_setprio(0);
    __builtin_amdgcn_s_barrier();

    // ---- phase 3: Q2 A-operands (8 ds_read), stage (t+2).B0 ----
#pragma unroll
    for (int mi = 0; mi < 4; ++mi) {
      unsigned ad = arow0 + po + (unsigned)((mi + 4) * 2048);
      a_[mi][0] = dsr(ad); a_[mi][1] = dsr(ad ^ 64u);
    }
    if (t + 2 < nt) stage(t + 2, 0, 1);
    __builtin_amdgcn_s_barrier();
    asm volatile("s_waitcnt lgkmcnt(0)");
    __builtin_amdgcn_sched_barrier(0);
    __builtin_amdgcn_s_setprio(1);
#pragma unroll
    for (int mi = 0; mi < 4; ++mi)
#pragma unroll
      for (int nj = 0; nj < 2; ++nj)
#pragma unroll
        for (int kk = 0; kk < 2; ++kk)
          acc[mi + 4][nj] = MFMA16(a_[mi][kk], b0_[nj][kk], acc[mi + 4][nj]);
    __builtin_amdgcn_s_setprio(0);
    __builtin_amdgcn_s_barrier();

    // ---- phase 4: Q3 (0 ds_read), stage (t+2).A0, tile-end vmcnt ----
    if (t + 2 < nt) stage(t + 2, 0, 0);
    __builtin_amdgcn_s_barrier();
    __builtin_amdgcn_s_setprio(1);
#pragma unroll
    for (int mi = 0; mi < 4; ++mi)
#pragma unroll
      for (int nj = 0; nj < 2; ++nj)
#pragma unroll
        for (int kk = 0; kk < 2; ++kk)
          acc[mi + 4][nj + 2] = MFMA16(a_[mi][kk], b1_[nj][kk], acc[mi + 4][nj + 2]);
    __builtin_amdgcn_s_setprio(0);
    if (t + 2 < nt) asm volatile("s_waitcnt vmcnt(4)");
    else            asm volatile("s_waitcnt vmcnt(0)");
    __builtin_amdgcn_s_barrier();
  }

  // epilogue: bias + relu; C/D: col = lane&15, row = (lane>>4)*4 + r
  float biasv[4];
#pragma unroll
  for (int nj = 0; nj < 4; ++nj)
    biasv[nj] = bias[bn + wn * 64 + nj * 16 + ln15];

#pragma unroll
  for (int mi = 0; mi < 8; ++mi) {
    int row0 = bm + wm * 128 + mi * 16 + (lane >> 4) * 4;
#pragma unroll
    for (int nj = 0; nj < 4; ++nj) {
      int col = bn + wn * 64 + nj * 16 + ln15;
#pragma unroll
      for (int r = 0; r < 4; ++r) {
        float v = acc[mi][nj][r] + biasv[nj];
        v = v > 0.f ? v : 0.f;
        size_t idx = (size_t)(row0 + r) * N + col;
        Cb[idx] = __float2bfloat16(v);
        if (Cf) Cf[idx] = v;
      }
    }
  }
}

// ---------------------------------------------------------------------------
// m97-structure 128x128 GEMM for the small-N layers (L3-L5).
// ---------------------------------------------------------------------------
__global__ __launch_bounds__(256, 2) void gemm_bt(
    const __hip_bfloat16* __restrict__ A,
    const __hip_bfloat16* __restrict__ Bt,
    const float* __restrict__ bias,
    __hip_bfloat16* __restrict__ Cb,
    float* __restrict__ Cf,
    int N, int K) {
  __shared__ char lds[32768];

  const int tid  = threadIdx.x;
  const int lane = tid & 63;
  const int wid  = tid >> 6;
  const int wm   = wid >> 1;
  const int wn   = wid & 1;
  const int bm   = blockIdx.y * 128;
  const int bn   = blockIdx.x * 128;

  f32x4 acc[4][4] = {};

  const int srow = tid >> 3;
  const int sk   = (tid & 7) * 8;
  const int kTiles = K >> 6;

  for (int kt = 0; kt < kTiles; ++kt) {
    __syncthreads();
    const __hip_bfloat16* ga = A  + (size_t)(bm + srow) * K + kt * 64 + sk;
    const __hip_bfloat16* gb = Bt + (size_t)(bn + srow) * K + kt * 64 + sk;
#pragma unroll
    for (int p = 0; p < 4; ++p) {
      gload16(ga + (size_t)(p * 32) * K, &lds[p * 4096 + wid * 1024]);
      gload16(gb + (size_t)(p * 32) * K, &lds[16384 + p * 4096 + wid * 1024]);
    }
    __syncthreads();

#pragma unroll
    for (int kk = 0; kk < 2; ++kk) {
      short8 avec[4], bvec[4];
#pragma unroll
      for (int i = 0; i < 4; ++i) {
        int row = wm * 64 + i * 16 + (lane & 15);
        avec[i] = *(const short8*)&lds[row * 128 + kk * 64 + (lane >> 4) * 16];
      }
#pragma unroll
      for (int j = 0; j < 4; ++j) {
        int row = wn * 64 + j * 16 + (lane & 15);
        bvec[j] = *(const short8*)&lds[16384 + row * 128 + kk * 64 + (lane >> 4) * 16];
      }
#pragma unroll
      for (int i = 0; i < 4; ++i)
#pragma unroll
        for (int j = 0; j < 4; ++j)
          acc[i][j] = MFMA16(avec[i], bvec[j], acc[i][j]);
    }
  }

  float biasv[4];
#pragma unroll
  for (int j = 0; j < 4; ++j)
    biasv[j] = bias[bn + wn * 64 + j * 16 + (lane & 15)];

#pragma unroll
  for (int i = 0; i < 4; ++i) {
    int row0 = bm + wm * 64 + i * 16 + (lane >> 4) * 4;
#pragma unroll
    for (int j = 0; j < 4; ++j) {
      int col = bn + wn * 64 + j * 16 + (lane & 15);
#pragma unroll
      for (int r = 0; r < 4; ++r) {
        float v = acc[i][j][r] + biasv[j];
        v = v > 0.f ? v : 0.f;
        size_t idx = (size_t)(row0 + r) * N + col;
        Cb[idx] = __float2bfloat16(v);
        if (Cf) Cf[idx] = v;
      }
    }
  }
}

// ---------------------------------------------------------------------------
// Head: out[r] = sigmoid( sum(wide[r,:]) + dot(D[r,:], Wh[dom[r],:]) + bh[dom[r]] )
// ---------------------------------------------------------------------------
__global__ __launch_bounds__(256) void head_kernel(
    const float* __restrict__ wide,
    const __hip_bfloat16* __restrict__ D,
    const int* __restrict__ dom,
    const float* __restrict__ Wh,
    const float* __restrict__ bh,
    float* __restrict__ out, int B) {
  const int wid  = threadIdx.x >> 6;
  const int lane = threadIdx.x & 63;
  const int row  = blockIdx.x * 4 + wid;
  if (row >= B) return;
  const int dm = dom[row];

  f32x4 wv = ((const f32x4*)(wide + (size_t)row * 256))[lane];
  float tot = wv[0] + wv[1] + wv[2] + wv[3];

  const unsigned short* drow = (const unsigned short*)(D + (size_t)row * 256);
  ushort4 dv = ((const ushort4*)drow)[lane];
  f32x4 hv = ((const f32x4*)(Wh + (size_t)dm * 256))[lane];
  tot += bf_bits2f(dv.x) * hv[0] + bf_bits2f(dv.y) * hv[1] +
         bf_bits2f(dv.z) * hv[2] + bf_bits2f(dv.w) * hv[3];

#pragma unroll
  for (int off = 32; off > 0; off >>= 1) tot += __shfl_xor(tot, off);

  if (lane == 0) {
    float x = tot + bh[dm];
    out[row] = 1.f / (1.f + __expf(-x));
  }
}

// ---------------------------------------------------------------------------
extern "C" void kernel_launch(void* const* d_in, const int* in_sizes, int n_in,
                              void* d_out, int out_size, void* d_ws, size_t ws_size,
                              hipStream_t stream) {
  const float* wide = (const float*)d_in[0];
  const float* deep = (const float*)d_in[1];
  const int*   dom  = (const int*)d_in[2];
  const float* W1  = (const float*)d_in[3];
  const float* b1  = (const float*)d_in[4];
  const float* W2  = (const float*)d_in[5];
  const float* b2  = (const float*)d_in[6];
  const float* W3  = (const float*)d_in[7];
  const float* b3  = (const float*)d_in[8];
  const float* Wd1 = (const float*)d_in[9];
  const float* bd1 = (const float*)d_in[10];
  const float* Wd2 = (const float*)d_in[11];
  const float* bd2 = (const float*)d_in[12];
  const float* Wh  = (const float*)d_in[13];
  const float* bh  = (const float*)d_in[14];
  float* out = (float*)d_out;

  const int B = 16384;
  char* ws = (char*)d_ws;
  __hip_bfloat16* buf0 = (__hip_bfloat16*)ws;
  __hip_bfloat16* buf1 = (__hip_bfloat16*)(ws + 33554432ull);
  __hip_bfloat16* W1t  = (__hip_bfloat16*)(ws + 100663296ull);
  __hip_bfloat16* W2t  = W1t + 2048 * 1024;
  __hip_bfloat16* W3t  = W2t + 1024 * 2048;
  __hip_bfloat16* Wd1t = W3t + 512 * 1024;
  __hip_bfloat16* Wd2t = Wd1t + 512 * 512;

  transpose_convert<<<dim3(2048 / 64, 1024 / 64), 256, 0, stream>>>(W1, W1t, 1024, 2048);
  transpose_convert<<<dim3(1024 / 64, 2048 / 64), 256, 0, stream>>>(W2, W2t, 2048, 1024);
  transpose_convert<<<dim3(512 / 64, 1024 / 64), 256, 0, stream>>>(W3, W3t, 1024, 512);
  transpose_convert<<<dim3(512 / 64, 512 / 64), 256, 0, stream>>>(Wd1, Wd1t, 512, 512);
  transpose_convert<<<dim3(256 / 64, 512 / 64), 256, 0, stream>>>(Wd2, Wd2t, 512, 256);

  {
    int n8 = B * 1024 / 8;
    f32_to_bf16<<<(n8 + 255) / 256, 256, 0, stream>>>(deep, (unsigned short*)buf0, n8);
  }

  float* shared_out = out + B;
  float* d_out_f    = out + B + (size_t)B * 512;

  // L1: [B,1024] x [1024,2048] -> H1 (buf1)   [8-phase 256^2, 512 blocks]
  gemm_8p<<<dim3((2048 / 256) * (B / 256)), 512, 0, stream>>>(
      buf0, W1t, b1, buf1, nullptr, 2048, 1024, 2048 / 256);
  // L2: [B,2048] x [2048,1024] -> H2 (buf0)   [8-phase 256^2, 256 blocks]
  gemm_8p<<<dim3((1024 / 256) * (B / 256)), 512, 0, stream>>>(
      buf1, W2t, b2, buf0, nullptr, 1024, 2048, 1024 / 256);
  // L3: -> shared S (buf1 bf16 + fp32 out)
  gemm_bt<<<dim3(512 / 128, B / 128), 256, 0, stream>>>(buf0, W3t, b3, buf1, shared_out, 512, 1024);
  // L4: -> T1 (buf0)
  gemm_bt<<<dim3(512 / 128, B / 128), 256, 0, stream>>>(buf1, Wd1t, bd1, buf0, nullptr, 512, 512);
  // L5: -> D (buf1 bf16 + fp32 out)
  gemm_bt<<<dim3(256 / 128, B / 128), 256, 0, stream>>>(buf0, Wd2t, bd2, buf1, d_out_f, 256, 512);

  head_kernel<<<B / 4, 256, 0, stream>>>(wide, buf1, dom, Wh, bh, out, B);
}

// Round 4
// 234.159 us; speedup vs baseline: 1.2679x; 1.0271x over previous
//
#include <hip/hip_runtime.h>
#include <hip/hip_bf16.h>

// ---------------------------------------------------------------------------
// Wide&Deep forward: 5-layer GEMM chain (bf16 MFMA) + wide-sum + domain head.
// L1/L2: 256x256 single-barrier-per-phase pipelined kernel (T1-T5, wave-skew).
// L3-L5: m97-structure 128x128 kernel.
// ---------------------------------------------------------------------------

typedef __attribute__((ext_vector_type(8))) short short8;
typedef __attribute__((ext_vector_type(4))) float f32x4;

static __device__ __forceinline__ unsigned short f2bf_bits(float x) {
  __hip_bfloat16 h = __float2bfloat16(x);
  return __builtin_bit_cast(unsigned short, h);
}
static __device__ __forceinline__ float bf_bits2f(unsigned short u) {
  __hip_bfloat16 h = __builtin_bit_cast(__hip_bfloat16, u);
  return __bfloat162float(h);
}

static __device__ __forceinline__ void gload16(const void* g, void* l) {
  __builtin_amdgcn_global_load_lds(
      (const __attribute__((address_space(1))) void*)g,
      (__attribute__((address_space(3))) void*)l, 16, 0, 0);
}

static __device__ __forceinline__ unsigned lds_u32(const void* p) {
  return (unsigned)(uintptr_t)(const __attribute__((address_space(3))) void*)p;
}

// compiler-invisible LDS read
static __device__ __forceinline__ short8 dsr(unsigned addr) {
  short8 r;
  asm volatile("ds_read_b128 %0, %1" : "=v"(r) : "v"(addr));
  return r;
}

#define MFMA16(a, b, c) __builtin_amdgcn_mfma_f32_16x16x32_bf16((a), (b), (c), 0, 0, 0)

// ---------------------------------------------------------------------------
// Transpose-convert: W [K][N] f32 -> Wt [N][K] bf16
// ---------------------------------------------------------------------------
__global__ void transpose_convert(const float* __restrict__ W,
                                  __hip_bfloat16* __restrict__ Wt,
                                  int K, int N) {
  __shared__ float tile[64][65];
  const int k0 = blockIdx.y * 64;
  const int n0 = blockIdx.x * 64;
  const int t  = threadIdx.x;
  const int tn = t & 63;
  const int t4 = t >> 6;
#pragma unroll
  for (int p = 0; p < 16; ++p) {
    int kl = p * 4 + t4;
    tile[kl][tn] = W[(size_t)(k0 + kl) * N + (n0 + tn)];
  }
  __syncthreads();
#pragma unroll
  for (int p = 0; p < 16; ++p) {
    int nl = p * 4 + t4;
    Wt[(size_t)(n0 + nl) * K + (k0 + tn)] = __float2bfloat16(tile[tn][nl]);
  }
}

// ---------------------------------------------------------------------------
// f32 -> bf16 bulk convert
// ---------------------------------------------------------------------------
__global__ void f32_to_bf16(const float* __restrict__ in,
                            unsigned short* __restrict__ out, int n8) {
  int i = blockIdx.x * blockDim.x + threadIdx.x;
  if (i >= n8) return;
  const f32x4* p = (const f32x4*)in + (size_t)i * 2;
  f32x4 a = p[0], b = p[1];
  short8 o;
  o[0] = (short)f2bf_bits(a[0]); o[1] = (short)f2bf_bits(a[1]);
  o[2] = (short)f2bf_bits(a[2]); o[3] = (short)f2bf_bits(a[3]);
  o[4] = (short)f2bf_bits(b[0]); o[5] = (short)f2bf_bits(b[1]);
  o[6] = (short)f2bf_bits(b[2]); o[7] = (short)f2bf_bits(b[3]);
  *(short8*)(out + (size_t)i * 8) = o;
}

// ---------------------------------------------------------------------------
// 256x256 GEMM, BK=64, 8 waves 2x4, dbuf LDS 128KB, swizzled LDS, 4 phases/
// K-tile with ONE barrier per phase (wave-skew overlap of ds_read with MFMA).
// Hazard invariants:
//  - RAW (staged tile data): per-tile counted vmcnt BEFORE the p1 barrier;
//    the p1 barrier is the cross-wave publish point.
//  - WAR (stage overwrites live LDS): each stage into a region R is placed
//    AFTER a barrier that all waves reach only after their lgkmcnt(0) for
//    the last reads of R (lgkm0(p-1) precedes arrival at barrier(p)).
// Stage schedule: (t+1).B1 @p1, (t+1).A1 @p2, (t+2).B0 @p3, (t+2).A0 @p4.
// ---------------------------------------------------------------------------
__global__ __launch_bounds__(512, 2) void gemm_8p(
    const __hip_bfloat16* __restrict__ A,
    const __hip_bfloat16* __restrict__ Bt,
    const float* __restrict__ bias,
    __hip_bfloat16* __restrict__ Cb,
    float* __restrict__ Cf,
    int N, int K, int nbx) {
  __shared__ char lds[131072];  // buf(t&1)*65536 : A tile 32KB, B tile @+32768

  const int tid  = threadIdx.x;
  const int lane = tid & 63;
  const int wid  = tid >> 6;
  const int wm   = wid >> 2;   // 0..1 -> rows wm*128..+127
  const int wn   = wid & 3;    // 0..3 -> cols wn*64..+63

  // T1: bijective XCD swizzle (gridDim.x % 8 == 0)
  const int nwg = gridDim.x;
  const int cpx = nwg >> 3;
  const int id  = blockIdx.x;
  const int swz = (id & 7) * cpx + (id >> 3);
  const int bm  = (swz / nbx) * 256;
  const int bn  = (swz % nbx) * 256;

  const int ln15 = lane & 15;
  const unsigned cswz = (unsigned)((((lane >> 4) ^ (lane & 7)) << 4));

  const unsigned lbase = lds_u32(lds);
  const unsigned arow0 = lbase + (unsigned)(wm * 128 + ln15) * 128u + cswz;
  const unsigned brow0 = lbase + 32768u + (unsigned)(wn * 64 + ln15) * 128u + cswz;

  const int nt = K >> 6;

  // per-thread staging bases (row tid>>3, pre-swizzled source chunk)
  const int swc = (tid & 7) ^ ((tid >> 3) & 7);
  const __hip_bfloat16* baseA = A  + (size_t)(bm + (tid >> 3)) * K + swc * 8;
  const __hip_bfloat16* baseB = Bt + (size_t)(bn + (tid >> 3)) * K + swc * 8;
  const unsigned ldst0 = (unsigned)(wid * 1024);

  // stage one half-tile: 2 x global_load_lds (rows half*128+q*64+tid/8)
  auto stage = [&](int kt, int half, int isB) {
    const __hip_bfloat16* base = isB ? baseB : baseA;
    char* dst = lds + ((kt & 1) * 65536) + (isB ? 32768 : 0) + half * 16384;
#pragma unroll
    for (int q = 0; q < 2; ++q) {
      gload16(base + (size_t)((half * 128 + q * 64) * K + kt * 64),
              dst + q * 8192 + ldst0);
    }
  };

  f32x4 acc[8][4] = {};

  // prologue: tile0 all halves + tile1 {B0, A0}; waits happen at p1.
  stage(0, 0, 1); stage(0, 0, 0); stage(0, 1, 1); stage(0, 1, 0);
  if (nt > 1) { stage(1, 0, 1); stage(1, 0, 0); }

  for (int t = 0; t < nt; ++t) {
    const unsigned po = (unsigned)(t & 1) * 65536u;
    short8 a_[4][2], b0_[2][2], b1_[2][2];

    // ---- phase 1: publish tile t; Q0 (a0-3 x b0) ----
    if (t + 1 < nt) asm volatile("s_waitcnt vmcnt(4)");
    else            asm volatile("s_waitcnt vmcnt(0)");
    __builtin_amdgcn_s_barrier();          // publish: all waves' tile-t loads done
    // reads: kk0 group first (6), then kk1 group (6)
#pragma unroll
    for (int mi = 0; mi < 4; ++mi) a_[mi][0] = dsr(arow0 + po + (unsigned)(mi * 2048));
#pragma unroll
    for (int nj = 0; nj < 2; ++nj) b0_[nj][0] = dsr(brow0 + po + (unsigned)(nj * 2048));
#pragma unroll
    for (int mi = 0; mi < 4; ++mi) a_[mi][1] = dsr((arow0 + po + (unsigned)(mi * 2048)) ^ 64u);
#pragma unroll
    for (int nj = 0; nj < 2; ++nj) b0_[nj][1] = dsr((brow0 + po + (unsigned)(nj * 2048)) ^ 64u);
    if (t + 1 < nt) stage(t + 1, 1, 1);    // other buf: safe after p1 barrier
    asm volatile("s_waitcnt lgkmcnt(6)");  // kk0 group resident
    __builtin_amdgcn_sched_barrier(0);
    __builtin_amdgcn_s_setprio(1);
#pragma unroll
    for (int mi = 0; mi < 4; ++mi)
#pragma unroll
      for (int nj = 0; nj < 2; ++nj)
        acc[mi][nj] = MFMA16(a_[mi][0], b0_[nj][0], acc[mi][nj]);
    asm volatile("s_waitcnt lgkmcnt(0)");
    __builtin_amdgcn_sched_barrier(0);
#pragma unroll
    for (int mi = 0; mi < 4; ++mi)
#pragma unroll
      for (int nj = 0; nj < 2; ++nj)
        acc[mi][nj] = MFMA16(a_[mi][1], b0_[nj][1], acc[mi][nj]);
    __builtin_amdgcn_s_setprio(0);

    // ---- phase 2: Q1 (a0-3 x b1); reads+stage BEFORE barrier ----
#pragma unroll
    for (int nj = 0; nj < 2; ++nj) {
      unsigned bd = brow0 + po + (unsigned)((nj + 2) * 2048);
      b1_[nj][0] = dsr(bd); b1_[nj][1] = dsr(bd ^ 64u);
    }
    if (t + 1 < nt) stage(t + 1, 1, 0);    // other buf: safe (>= p1 barrier)
    __builtin_amdgcn_s_barrier();
    asm volatile("s_waitcnt lgkmcnt(0)");
    __builtin_amdgcn_sched_barrier(0);
    __builtin_amdgcn_s_setprio(1);
#pragma unroll
    for (int kk = 0; kk < 2; ++kk)
#pragma unroll
      for (int mi = 0; mi < 4; ++mi)
#pragma unroll
        for (int nj = 0; nj < 2; ++nj)
          acc[mi][nj + 2] = MFMA16(a_[mi][kk], b1_[nj][kk], acc[mi][nj + 2]);
    __builtin_amdgcn_s_setprio(0);

    // ---- phase 3: Q2 (a4-7 x b0); stage B0(t+2) AFTER barrier (WAR) ----
#pragma unroll
    for (int mi = 0; mi < 4; ++mi) {
      unsigned ad = arow0 + po + (unsigned)((mi + 4) * 2048);
      a_[mi][0] = dsr(ad); a_[mi][1] = dsr(ad ^ 64u);
    }
    __builtin_amdgcn_s_barrier();          // all waves' B reads (p1,p2) retired
    if (t + 2 < nt) stage(t + 2, 0, 1);
    asm volatile("s_waitcnt lgkmcnt(0)");
    __builtin_amdgcn_sched_barrier(0);
    __builtin_amdgcn_s_setprio(1);
#pragma unroll
    for (int kk = 0; kk < 2; ++kk)
#pragma unroll
      for (int mi = 0; mi < 4; ++mi)
#pragma unroll
        for (int nj = 0; nj < 2; ++nj)
          acc[mi + 4][nj] = MFMA16(a_[mi][kk], b0_[nj][kk], acc[mi + 4][nj]);
    __builtin_amdgcn_s_setprio(0);

    // ---- phase 4: Q3 (a4-7 x b1); stage A0(t+2) AFTER barrier (WAR) ----
    __builtin_amdgcn_s_barrier();          // all waves' A reads (p1,p3) retired
    if (t + 2 < nt) stage(t + 2, 0, 0);
    __builtin_amdgcn_s_setprio(1);
#pragma unroll
    for (int kk = 0; kk < 2; ++kk)
#pragma unroll
      for (int mi = 0; mi < 4; ++mi)
#pragma unroll
        for (int nj = 0; nj < 2; ++nj)
          acc[mi + 4][nj + 2] = MFMA16(a_[mi][kk], b1_[nj][kk], acc[mi + 4][nj + 2]);
    __builtin_amdgcn_s_setprio(0);
  }

  // epilogue: bias + relu; C/D: col = lane&15, row = (lane>>4)*4 + r
  float biasv[4];
#pragma unroll
  for (int nj = 0; nj < 4; ++nj)
    biasv[nj] = bias[bn + wn * 64 + nj * 16 + ln15];

#pragma unroll
  for (int mi = 0; mi < 8; ++mi) {
    int row0 = bm + wm * 128 + mi * 16 + (lane >> 4) * 4;
#pragma unroll
    for (int nj = 0; nj < 4; ++nj) {
      int col = bn + wn * 64 + nj * 16 + ln15;
#pragma unroll
      for (int r = 0; r < 4; ++r) {
        float v = acc[mi][nj][r] + biasv[nj];
        v = v > 0.f ? v : 0.f;
        size_t idx = (size_t)(row0 + r) * N + col;
        Cb[idx] = __float2bfloat16(v);
        if (Cf) Cf[idx] = v;
      }
    }
  }
}

// ---------------------------------------------------------------------------
// m97-structure 128x128 GEMM for the small-N layers (L3-L5).
// ---------------------------------------------------------------------------
__global__ __launch_bounds__(256, 2) void gemm_bt(
    const __hip_bfloat16* __restrict__ A,
    const __hip_bfloat16* __restrict__ Bt,
    const float* __restrict__ bias,
    __hip_bfloat16* __restrict__ Cb,
    float* __restrict__ Cf,
    int N, int K) {
  __shared__ char lds[32768];

  const int tid  = threadIdx.x;
  const int lane = tid & 63;
  const int wid  = tid >> 6;
  const int wm   = wid >> 1;
  const int wn   = wid & 1;
  const int bm   = blockIdx.y * 128;
  const int bn   = blockIdx.x * 128;

  f32x4 acc[4][4] = {};

  const int srow = tid >> 3;
  const int sk   = (tid & 7) * 8;
  const int kTiles = K >> 6;

  for (int kt = 0; kt < kTiles; ++kt) {
    __syncthreads();
    const __hip_bfloat16* ga = A  + (size_t)(bm + srow) * K + kt * 64 + sk;
    const __hip_bfloat16* gb = Bt + (size_t)(bn + srow) * K + kt * 64 + sk;
#pragma unroll
    for (int p = 0; p < 4; ++p) {
      gload16(ga + (size_t)(p * 32) * K, &lds[p * 4096 + wid * 1024]);
      gload16(gb + (size_t)(p * 32) * K, &lds[16384 + p * 4096 + wid * 1024]);
    }
    __syncthreads();

#pragma unroll
    for (int kk = 0; kk < 2; ++kk) {
      short8 avec[4], bvec[4];
#pragma unroll
      for (int i = 0; i < 4; ++i) {
        int row = wm * 64 + i * 16 + (lane & 15);
        avec[i] = *(const short8*)&lds[row * 128 + kk * 64 + (lane >> 4) * 16];
      }
#pragma unroll
      for (int j = 0; j < 4; ++j) {
        int row = wn * 64 + j * 16 + (lane & 15);
        bvec[j] = *(const short8*)&lds[16384 + row * 128 + kk * 64 + (lane >> 4) * 16];
      }
#pragma unroll
      for (int i = 0; i < 4; ++i)
#pragma unroll
        for (int j = 0; j < 4; ++j)
          acc[i][j] = MFMA16(avec[i], bvec[j], acc[i][j]);
    }
  }

  float biasv[4];
#pragma unroll
  for (int j = 0; j < 4; ++j)
    biasv[j] = bias[bn + wn * 64 + j * 16 + (lane & 15)];

#pragma unroll
  for (int i = 0; i < 4; ++i) {
    int row0 = bm + wm * 64 + i * 16 + (lane >> 4) * 4;
#pragma unroll
    for (int j = 0; j < 4; ++j) {
      int col = bn + wn * 64 + j * 16 + (lane & 15);
#pragma unroll
      for (int r = 0; r < 4; ++r) {
        float v = acc[i][j][r] + biasv[j];
        v = v > 0.f ? v : 0.f;
        size_t idx = (size_t)(row0 + r) * N + col;
        Cb[idx] = __float2bfloat16(v);
        if (Cf) Cf[idx] = v;
      }
    }
  }
}

// ---------------------------------------------------------------------------
// Head: out[r] = sigmoid( sum(wide[r,:]) + dot(D[r,:], Wh[dom[r],:]) + bh[dom[r]] )
// ---------------------------------------------------------------------------
__global__ __launch_bounds__(256) void head_kernel(
    const float* __restrict__ wide,
    const __hip_bfloat16* __restrict__ D,
    const int* __restrict__ dom,
    const float* __restrict__ Wh,
    const float* __restrict__ bh,
    float* __restrict__ out, int B) {
  const int wid  = threadIdx.x >> 6;
  const int lane = threadIdx.x & 63;
  const int row  = blockIdx.x * 4 + wid;
  if (row >= B) return;
  const int dm = dom[row];

  f32x4 wv = ((const f32x4*)(wide + (size_t)row * 256))[lane];
  float tot = wv[0] + wv[1] + wv[2] + wv[3];

  const unsigned short* drow = (const unsigned short*)(D + (size_t)row * 256);
  ushort4 dv = ((const ushort4*)drow)[lane];
  f32x4 hv = ((const f32x4*)(Wh + (size_t)dm * 256))[lane];
  tot += bf_bits2f(dv.x) * hv[0] + bf_bits2f(dv.y) * hv[1] +
         bf_bits2f(dv.z) * hv[2] + bf_bits2f(dv.w) * hv[3];

#pragma unroll
  for (int off = 32; off > 0; off >>= 1) tot += __shfl_xor(tot, off);

  if (lane == 0) {
    float x = tot + bh[dm];
    out[row] = 1.f / (1.f + __expf(-x));
  }
}

// ---------------------------------------------------------------------------
extern "C" void kernel_launch(void* const* d_in, const int* in_sizes, int n_in,
                              void* d_out, int out_size, void* d_ws, size_t ws_size,
                              hipStream_t stream) {
  const float* wide = (const float*)d_in[0];
  const float* deep = (const float*)d_in[1];
  const int*   dom  = (const int*)d_in[2];
  const float* W1  = (const float*)d_in[3];
  const float* b1  = (const float*)d_in[4];
  const float* W2  = (const float*)d_in[5];
  const float* b2  = (const float*)d_in[6];
  const float* W3  = (const float*)d_in[7];
  const float* b3  = (const float*)d_in[8];
  const float* Wd1 = (const float*)d_in[9];
  const float* bd1 = (const float*)d_in[10];
  const float* Wd2 = (const float*)d_in[11];
  const float* bd2 = (const float*)d_in[12];
  const float* Wh  = (const float*)d_in[13];
  const float* bh  = (const float*)d_in[14];
  float* out = (float*)d_out;

  const int B = 16384;
  char* ws = (char*)d_ws;
  __hip_bfloat16* buf0 = (__hip_bfloat16*)ws;
  __hip_bfloat16* buf1 = (__hip_bfloat16*)(ws + 33554432ull);
  __hip_bfloat16* W1t  = (__hip_bfloat16*)(ws + 100663296ull);
  __hip_bfloat16* W2t  = W1t + 2048 * 1024;
  __hip_bfloat16* W3t  = W2t + 1024 * 2048;
  __hip_bfloat16* Wd1t = W3t + 512 * 1024;
  __hip_bfloat16* Wd2t = Wd1t + 512 * 512;

  transpose_convert<<<dim3(2048 / 64, 1024 / 64), 256, 0, stream>>>(W1, W1t, 1024, 2048);
  transpose_convert<<<dim3(1024 / 64, 2048 / 64), 256, 0, stream>>>(W2, W2t, 2048, 1024);
  transpose_convert<<<dim3(512 / 64, 1024 / 64), 256, 0, stream>>>(W3, W3t, 1024, 512);
  transpose_convert<<<dim3(512 / 64, 512 / 64), 256, 0, stream>>>(Wd1, Wd1t, 512, 512);
  transpose_convert<<<dim3(256 / 64, 512 / 64), 256, 0, stream>>>(Wd2, Wd2t, 512, 256);

  {
    int n8 = B * 1024 / 8;
    f32_to_bf16<<<(n8 + 255) / 256, 256, 0, stream>>>(deep, (unsigned short*)buf0, n8);
  }

  float* shared_out = out + B;
  float* d_out_f    = out + B + (size_t)B * 512;

  // L1: [B,1024] x [1024,2048] -> H1 (buf1)
  gemm_8p<<<dim3((2048 / 256) * (B / 256)), 512, 0, stream>>>(
      buf0, W1t, b1, buf1, nullptr, 2048, 1024, 2048 / 256);
  // L2: [B,2048] x [2048,1024] -> H2 (buf0)
  gemm_8p<<<dim3((1024 / 256) * (B / 256)), 512, 0, stream>>>(
      buf1, W2t, b2, buf0, nullptr, 1024, 2048, 1024 / 256);
  // L3: -> shared S (buf1 bf16 + fp32 out)
  gemm_bt<<<dim3(512 / 128, B / 128), 256, 0, stream>>>(buf0, W3t, b3, buf1, shared_out, 512, 1024);
  // L4: -> T1 (buf0)
  gemm_bt<<<dim3(512 / 128, B / 128), 256, 0, stream>>>(buf1, Wd1t, bd1, buf0, nullptr, 512, 512);
  // L5: -> D (buf1 bf16 + fp32 out)
  gemm_bt<<<dim3(256 / 128, B / 128), 256, 0, stream>>>(buf0, Wd2t, bd2, buf1, d_out_f, 256, 512);

  head_kernel<<<B / 4, 256, 0, stream>>>(wide, buf1, dom, Wh, bh, out, B);
}

// Round 5
// 227.280 us; speedup vs baseline: 1.3063x; 1.0303x over previous
//
#include <hip/hip_runtime.h>
#include <hip/hip_bf16.h>

// ---------------------------------------------------------------------------
// Wide&Deep forward: 5-layer GEMM chain (bf16 MFMA) + wide-sum + domain head.
// L1: gemm_8p (R4 schedule, control). L2: gemm_8pq (read-ahead pipelined).
// L3/L4: gemm_128 (128x256 tile). L5: gemm_bt. + converts + head.
// ---------------------------------------------------------------------------

typedef __attribute__((ext_vector_type(8))) short short8;
typedef __attribute__((ext_vector_type(4))) float f32x4;

static __device__ __forceinline__ unsigned short f2bf_bits(float x) {
  __hip_bfloat16 h = __float2bfloat16(x);
  return __builtin_bit_cast(unsigned short, h);
}
static __device__ __forceinline__ float bf_bits2f(unsigned short u) {
  __hip_bfloat16 h = __builtin_bit_cast(__hip_bfloat16, u);
  return __bfloat162float(h);
}

static __device__ __forceinline__ void gload16(const void* g, void* l) {
  __builtin_amdgcn_global_load_lds(
      (const __attribute__((address_space(1))) void*)g,
      (__attribute__((address_space(3))) void*)l, 16, 0, 0);
}

static __device__ __forceinline__ unsigned lds_u32(const void* p) {
  return (unsigned)(uintptr_t)(const __attribute__((address_space(3))) void*)p;
}

// compiler-invisible LDS read
static __device__ __forceinline__ short8 dsr(unsigned addr) {
  short8 r;
  asm volatile("ds_read_b128 %0, %1" : "=v"(r) : "v"(addr));
  return r;
}

#define MFMA16(a, b, c) __builtin_amdgcn_mfma_f32_16x16x32_bf16((a), (b), (c), 0, 0, 0)
#define SB0() __builtin_amdgcn_sched_barrier(0)
#define PRIO(x) __builtin_amdgcn_s_setprio(x)
#define BAR() __builtin_amdgcn_s_barrier()

// ---------------------------------------------------------------------------
// Transpose-convert: W [K][N] f32 -> Wt [N][K] bf16
// ---------------------------------------------------------------------------
__global__ void transpose_convert(const float* __restrict__ W,
                                  __hip_bfloat16* __restrict__ Wt,
                                  int K, int N) {
  __shared__ float tile[64][65];
  const int k0 = blockIdx.y * 64;
  const int n0 = blockIdx.x * 64;
  const int t  = threadIdx.x;
  const int tn = t & 63;
  const int t4 = t >> 6;
#pragma unroll
  for (int p = 0; p < 16; ++p) {
    int kl = p * 4 + t4;
    tile[kl][tn] = W[(size_t)(k0 + kl) * N + (n0 + tn)];
  }
  __syncthreads();
#pragma unroll
  for (int p = 0; p < 16; ++p) {
    int nl = p * 4 + t4;
    Wt[(size_t)(n0 + nl) * K + (k0 + tn)] = __float2bfloat16(tile[tn][nl]);
  }
}

// ---------------------------------------------------------------------------
// f32 -> bf16 bulk convert
// ---------------------------------------------------------------------------
__global__ void f32_to_bf16(const float* __restrict__ in,
                            unsigned short* __restrict__ out, int n8) {
  int i = blockIdx.x * blockDim.x + threadIdx.x;
  if (i >= n8) return;
  const f32x4* p = (const f32x4*)in + (size_t)i * 2;
  f32x4 a = p[0], b = p[1];
  short8 o;
  o[0] = (short)f2bf_bits(a[0]); o[1] = (short)f2bf_bits(a[1]);
  o[2] = (short)f2bf_bits(a[2]); o[3] = (short)f2bf_bits(a[3]);
  o[4] = (short)f2bf_bits(b[0]); o[5] = (short)f2bf_bits(b[1]);
  o[6] = (short)f2bf_bits(b[2]); o[7] = (short)f2bf_bits(b[3]);
  *(short8*)(out + (size_t)i * 8) = o;
}

// ---------------------------------------------------------------------------
// gemm_8p: 256x256, R4 schedule (control, unchanged from round 4).
// ---------------------------------------------------------------------------
__global__ __launch_bounds__(512, 2) void gemm_8p(
    const __hip_bfloat16* __restrict__ A,
    const __hip_bfloat16* __restrict__ Bt,
    const float* __restrict__ bias,
    __hip_bfloat16* __restrict__ Cb,
    float* __restrict__ Cf,
    int N, int K, int nbx) {
  __shared__ char lds[131072];

  const int tid  = threadIdx.x;
  const int lane = tid & 63;
  const int wid  = tid >> 6;
  const int wm   = wid >> 2;
  const int wn   = wid & 3;

  const int nwg = gridDim.x;
  const int cpx = nwg >> 3;
  const int id  = blockIdx.x;
  const int swz = (id & 7) * cpx + (id >> 3);
  const int bm  = (swz / nbx) * 256;
  const int bn  = (swz % nbx) * 256;

  const int ln15 = lane & 15;
  const unsigned cswz = (unsigned)((((lane >> 4) ^ (lane & 7)) << 4));

  const unsigned lbase = lds_u32(lds);
  const unsigned arow0 = lbase + (unsigned)(wm * 128 + ln15) * 128u + cswz;
  const unsigned brow0 = lbase + 32768u + (unsigned)(wn * 64 + ln15) * 128u + cswz;

  const int nt = K >> 6;

  const int swc = (tid & 7) ^ ((tid >> 3) & 7);
  const __hip_bfloat16* baseA = A  + (size_t)(bm + (tid >> 3)) * K + swc * 8;
  const __hip_bfloat16* baseB = Bt + (size_t)(bn + (tid >> 3)) * K + swc * 8;
  const unsigned ldst0 = (unsigned)(wid * 1024);

  auto stage = [&](int kt, int half, int isB) {
    const __hip_bfloat16* base = isB ? baseB : baseA;
    char* dst = lds + ((kt & 1) * 65536) + (isB ? 32768 : 0) + half * 16384;
#pragma unroll
    for (int q = 0; q < 2; ++q) {
      gload16(base + (size_t)((half * 128 + q * 64) * K + kt * 64),
              dst + q * 8192 + ldst0);
    }
  };

  f32x4 acc[8][4] = {};

  stage(0, 0, 1); stage(0, 0, 0); stage(0, 1, 1); stage(0, 1, 0);
  if (nt > 1) { stage(1, 0, 1); stage(1, 0, 0); }

  for (int t = 0; t < nt; ++t) {
    const unsigned po = (unsigned)(t & 1) * 65536u;
    short8 a_[4][2], b0_[2][2], b1_[2][2];

    if (t + 1 < nt) asm volatile("s_waitcnt vmcnt(4)");
    else            asm volatile("s_waitcnt vmcnt(0)");
    BAR();
#pragma unroll
    for (int mi = 0; mi < 4; ++mi) a_[mi][0] = dsr(arow0 + po + (unsigned)(mi * 2048));
#pragma unroll
    for (int nj = 0; nj < 2; ++nj) b0_[nj][0] = dsr(brow0 + po + (unsigned)(nj * 2048));
#pragma unroll
    for (int mi = 0; mi < 4; ++mi) a_[mi][1] = dsr((arow0 + po + (unsigned)(mi * 2048)) ^ 64u);
#pragma unroll
    for (int nj = 0; nj < 2; ++nj) b0_[nj][1] = dsr((brow0 + po + (unsigned)(nj * 2048)) ^ 64u);
    if (t + 1 < nt) stage(t + 1, 1, 1);
    asm volatile("s_waitcnt lgkmcnt(6)");
    SB0();
    PRIO(1);
#pragma unroll
    for (int mi = 0; mi < 4; ++mi)
#pragma unroll
      for (int nj = 0; nj < 2; ++nj)
        acc[mi][nj] = MFMA16(a_[mi][0], b0_[nj][0], acc[mi][nj]);
    asm volatile("s_waitcnt lgkmcnt(0)");
    SB0();
#pragma unroll
    for (int mi = 0; mi < 4; ++mi)
#pragma unroll
      for (int nj = 0; nj < 2; ++nj)
        acc[mi][nj] = MFMA16(a_[mi][1], b0_[nj][1], acc[mi][nj]);
    PRIO(0);

#pragma unroll
    for (int nj = 0; nj < 2; ++nj) {
      unsigned bd = brow0 + po + (unsigned)((nj + 2) * 2048);
      b1_[nj][0] = dsr(bd); b1_[nj][1] = dsr(bd ^ 64u);
    }
    if (t + 1 < nt) stage(t + 1, 1, 0);
    BAR();
    asm volatile("s_waitcnt lgkmcnt(0)");
    SB0();
    PRIO(1);
#pragma unroll
    for (int kk = 0; kk < 2; ++kk)
#pragma unroll
      for (int mi = 0; mi < 4; ++mi)
#pragma unroll
        for (int nj = 0; nj < 2; ++nj)
          acc[mi][nj + 2] = MFMA16(a_[mi][kk], b1_[nj][kk], acc[mi][nj + 2]);
    PRIO(0);

#pragma unroll
    for (int mi = 0; mi < 4; ++mi) {
      unsigned ad = arow0 + po + (unsigned)((mi + 4) * 2048);
      a_[mi][0] = dsr(ad); a_[mi][1] = dsr(ad ^ 64u);
    }
    BAR();
    if (t + 2 < nt) stage(t + 2, 0, 1);
    asm volatile("s_waitcnt lgkmcnt(0)");
    SB0();
    PRIO(1);
#pragma unroll
    for (int kk = 0; kk < 2; ++kk)
#pragma unroll
      for (int mi = 0; mi < 4; ++mi)
#pragma unroll
        for (int nj = 0; nj < 2; ++nj)
          acc[mi + 4][nj] = MFMA16(a_[mi][kk], b0_[nj][kk], acc[mi + 4][nj]);
    PRIO(0);

    BAR();
    if (t + 2 < nt) stage(t + 2, 0, 0);
    PRIO(1);
#pragma unroll
    for (int kk = 0; kk < 2; ++kk)
#pragma unroll
      for (int mi = 0; mi < 4; ++mi)
#pragma unroll
        for (int nj = 0; nj < 2; ++nj)
          acc[mi + 4][nj + 2] = MFMA16(a_[mi][kk], b1_[nj][kk], acc[mi + 4][nj + 2]);
    PRIO(0);
  }

  float biasv[4];
#pragma unroll
  for (int nj = 0; nj < 4; ++nj)
    biasv[nj] = bias[bn + wn * 64 + nj * 16 + ln15];

#pragma unroll
  for (int mi = 0; mi < 8; ++mi) {
    int row0 = bm + wm * 128 + mi * 16 + (lane >> 4) * 4;
#pragma unroll
    for (int nj = 0; nj < 4; ++nj) {
      int col = bn + wn * 64 + nj * 16 + ln15;
#pragma unroll
      for (int r = 0; r < 4; ++r) {
        float v = acc[mi][nj][r] + biasv[nj];
        v = v > 0.f ? v : 0.f;
        size_t idx = (size_t)(row0 + r) * N + col;
        Cb[idx] = __float2bfloat16(v);
        if (Cf) Cf[idx] = v;
      }
    }
  }
}

// ---------------------------------------------------------------------------
// gemm_8pq: 256x256, read-ahead pipelined variant (every phase's MFMA gates
// on ds_reads issued >=1 phase earlier; lgkm0 at phase top is ~free).
// Read schedule: b0/b1(t)@P1-top (partial-gated kk0), aHi(t)@P2-top,
// aLo(t+1)@P4-top. Publish invariant: vmcnt(2)@P3-end retires ALL of tile
// t+1's staging ((t+1).A1 is the last-staged half) before barrier(P3)->P4.
// Stage schedule: (t+1).B1@P1, (t+1).A1@P2, (t+2).B0@P3, (t+2).A0@P4.
// ---------------------------------------------------------------------------
__global__ __launch_bounds__(512, 2) void gemm_8pq(
    const __hip_bfloat16* __restrict__ A,
    const __hip_bfloat16* __restrict__ Bt,
    const float* __restrict__ bias,
    __hip_bfloat16* __restrict__ Cb,
    int N, int K, int nbx) {
  __shared__ char lds[131072];

  const int tid  = threadIdx.x;
  const int lane = tid & 63;
  const int wid  = tid >> 6;
  const int wm   = wid >> 2;
  const int wn   = wid & 3;

  const int nwg = gridDim.x;
  const int cpx = nwg >> 3;
  const int id  = blockIdx.x;
  const int swz = (id & 7) * cpx + (id >> 3);
  const int bm  = (swz / nbx) * 256;
  const int bn  = (swz % nbx) * 256;

  const int ln15 = lane & 15;
  const unsigned cswz = (unsigned)((((lane >> 4) ^ (lane & 7)) << 4));

  const unsigned lbase = lds_u32(lds);
  const unsigned arow0 = lbase + (unsigned)(wm * 128 + ln15) * 128u + cswz;
  const unsigned brow0 = lbase + 32768u + (unsigned)(wn * 64 + ln15) * 128u + cswz;

  const int nt = K >> 6;

  const int swc = (tid & 7) ^ ((tid >> 3) & 7);
  const __hip_bfloat16* baseA = A  + (size_t)(bm + (tid >> 3)) * K + swc * 8;
  const __hip_bfloat16* baseB = Bt + (size_t)(bn + (tid >> 3)) * K + swc * 8;
  const unsigned ldst0 = (unsigned)(wid * 1024);

  auto stage = [&](int kt, int half, int isB) {
    const __hip_bfloat16* base = isB ? baseB : baseA;
    char* dst = lds + ((kt & 1) * 65536) + (isB ? 32768 : 0) + half * 16384;
#pragma unroll
    for (int q = 0; q < 2; ++q) {
      gload16(base + (size_t)((half * 128 + q * 64) * K + kt * 64),
              dst + q * 8192 + ldst0);
    }
  };

  f32x4 acc[8][4] = {};
  short8 aLo[4][2], aHi[4][2], b0v[2][2], b1v[2][2];

  // prologue: tile0 {B0,A0,B1,A1}, tile1 {B0,A0}; publish tile0; read aLo(0)
  stage(0, 0, 1); stage(0, 0, 0); stage(0, 1, 1); stage(0, 1, 0);
  if (nt > 1) {
    stage(1, 0, 1); stage(1, 0, 0);
    asm volatile("s_waitcnt vmcnt(4)");
  } else {
    asm volatile("s_waitcnt vmcnt(0)");
  }
  BAR();
#pragma unroll
  for (int mi = 0; mi < 4; ++mi) {
    unsigned ad = arow0 + (unsigned)(mi * 2048);
    aLo[mi][0] = dsr(ad); aLo[mi][1] = dsr(ad ^ 64u);
  }

  for (int t = 0; t < nt; ++t) {
    const unsigned po = (unsigned)(t & 1) * 65536u;
    const unsigned pn = po ^ 65536u;

    // ---- P1: read b0,b1(t); MFMA aLo x b0 (kk0 gated on 2 reads) ----
    asm volatile("s_waitcnt lgkmcnt(0)");  // aLo(t) reads done (issued P4(t-1))
    SB0();
#pragma unroll
    for (int nj = 0; nj < 2; ++nj) b0v[nj][0] = dsr(brow0 + po + (unsigned)(nj * 2048));
#pragma unroll
    for (int nj = 0; nj < 2; ++nj) b0v[nj][1] = dsr((brow0 + po + (unsigned)(nj * 2048)) ^ 64u);
#pragma unroll
    for (int nj = 0; nj < 2; ++nj) b1v[nj][0] = dsr(brow0 + po + (unsigned)((nj + 2) * 2048));
#pragma unroll
    for (int nj = 0; nj < 2; ++nj) b1v[nj][1] = dsr((brow0 + po + (unsigned)((nj + 2) * 2048)) ^ 64u);
    asm volatile("s_waitcnt lgkmcnt(6)");  // b0 kk0 resident
    SB0();
    PRIO(1);
#pragma unroll
    for (int mi = 0; mi < 4; ++mi)
#pragma unroll
      for (int nj = 0; nj < 2; ++nj)
        acc[mi][nj] = MFMA16(aLo[mi][0], b0v[nj][0], acc[mi][nj]);
    asm volatile("s_waitcnt lgkmcnt(4)");  // b0 kk1 resident
    SB0();
#pragma unroll
    for (int mi = 0; mi < 4; ++mi)
#pragma unroll
      for (int nj = 0; nj < 2; ++nj)
        acc[mi][nj] = MFMA16(aLo[mi][1], b0v[nj][1], acc[mi][nj]);
    PRIO(0);
    if (t + 1 < nt) stage(t + 1, 1, 1);
    BAR();

    // ---- P2: read aHi(t); MFMA aLo x b1 (gated free) ----
    asm volatile("s_waitcnt lgkmcnt(0)");  // b1(t) reads done
    SB0();
#pragma unroll
    for (int mi = 0; mi < 4; ++mi) {
      unsigned ad = arow0 + po + (unsigned)((mi + 4) * 2048);
      aHi[mi][0] = dsr(ad); aHi[mi][1] = dsr(ad ^ 64u);
    }
    PRIO(1);
#pragma unroll
    for (int kk = 0; kk < 2; ++kk)
#pragma unroll
      for (int mi = 0; mi < 4; ++mi)
#pragma unroll
        for (int nj = 0; nj < 2; ++nj)
          acc[mi][nj + 2] = MFMA16(aLo[mi][kk], b1v[nj][kk], acc[mi][nj + 2]);
    PRIO(0);
    if (t + 1 < nt) stage(t + 1, 1, 0);
    BAR();

    // ---- P3: MFMA aHi x b0; publish tile t+1 (vmcnt before barrier) ----
    asm volatile("s_waitcnt lgkmcnt(0)");  // aHi(t) reads done
    SB0();
    PRIO(1);
#pragma unroll
    for (int kk = 0; kk < 2; ++kk)
#pragma unroll
      for (int mi = 0; mi < 4; ++mi)
#pragma unroll
        for (int nj = 0; nj < 2; ++nj)
          acc[mi + 4][nj] = MFMA16(aHi[mi][kk], b0v[nj][kk], acc[mi + 4][nj]);
    PRIO(0);
    if (t + 2 < nt) stage(t + 2, 0, 1);
    if (t + 1 < nt) {
      if (t + 2 < nt) asm volatile("s_waitcnt vmcnt(2)");
      else            asm volatile("s_waitcnt vmcnt(0)");
    }
    BAR();

    // ---- P4: read aLo(t+1); MFMA aHi x b1 ----
    SB0();
    if (t + 1 < nt) {
#pragma unroll
      for (int mi = 0; mi < 4; ++mi) {
        unsigned ad = arow0 + pn + (unsigned)(mi * 2048);
        aLo[mi][0] = dsr(ad); aLo[mi][1] = dsr(ad ^ 64u);
      }
    }
    PRIO(1);
#pragma unroll
    for (int kk = 0; kk < 2; ++kk)
#pragma unroll
      for (int mi = 0; mi < 4; ++mi)
#pragma unroll
        for (int nj = 0; nj < 2; ++nj)
          acc[mi + 4][nj + 2] = MFMA16(aHi[mi][kk], b1v[nj][kk], acc[mi + 4][nj + 2]);
    PRIO(0);
    if (t + 2 < nt) stage(t + 2, 0, 0);
    BAR();
  }

  float biasv[4];
#pragma unroll
  for (int nj = 0; nj < 4; ++nj)
    biasv[nj] = bias[bn + wn * 64 + nj * 16 + ln15];

#pragma unroll
  for (int mi = 0; mi < 8; ++mi) {
    int row0 = bm + wm * 128 + mi * 16 + (lane >> 4) * 4;
#pragma unroll
    for (int nj = 0; nj < 4; ++nj) {
      int col = bn + wn * 64 + nj * 16 + ln15;
#pragma unroll
      for (int r = 0; r < 4; ++r) {
        float v = acc[mi][nj][r] + biasv[nj];
        v = v > 0.f ? v : 0.f;
        Cb[(size_t)(row0 + r) * N + col] = __float2bfloat16(v);
      }
    }
  }
}

// ---------------------------------------------------------------------------
// gemm_128: 128x256 tile (BM=128, BN=256, BK=64), 8 waves 2x4, wave-tile
// 64x64, R4-style schedule. For N=512/256-class layers (grid = 256 blocks).
// LDS: A [128][64] @0 (16KB), B [256][64] @16384 (32KB), buf stride 49152.
// Stage: A-half = 64 rows (1 gload/thread), B-half = 128 rows (2 gloads).
// ---------------------------------------------------------------------------
__global__ __launch_bounds__(512, 2) void gemm_128(
    const __hip_bfloat16* __restrict__ A,
    const __hip_bfloat16* __restrict__ Bt,
    const float* __restrict__ bias,
    __hip_bfloat16* __restrict__ Cb,
    float* __restrict__ Cf,
    int N, int K, int nbx) {
  __shared__ char lds[98304];

  const int tid  = threadIdx.x;
  const int lane = tid & 63;
  const int wid  = tid >> 6;
  const int wm   = wid >> 2;   // 0..1 -> rows wm*64
  const int wn   = wid & 3;    // 0..3 -> cols wn*64

  const int nwg = gridDim.x;
  const int cpx = nwg >> 3;
  const int id  = blockIdx.x;
  const int swz = (id & 7) * cpx + (id >> 3);
  const int bm  = (swz / nbx) * 128;
  const int bn  = (swz % nbx) * 256;

  const int ln15 = lane & 15;
  const unsigned cswz = (unsigned)((((lane >> 4) ^ (lane & 7)) << 4));

  const unsigned lbase = lds_u32(lds);
  const unsigned arow0 = lbase + (unsigned)(wm * 64 + ln15) * 128u + cswz;
  const unsigned brow0 = lbase + 16384u + (unsigned)(wn * 64 + ln15) * 128u + cswz;

  const int nt = K >> 6;

  const int swc = (tid & 7) ^ ((tid >> 3) & 7);
  const __hip_bfloat16* baseA = A  + (size_t)(bm + (tid >> 3)) * K + swc * 8;
  const __hip_bfloat16* baseB = Bt + (size_t)(bn + (tid >> 3)) * K + swc * 8;
  const unsigned ldst0 = (unsigned)(tid * 16);

  auto stageA = [&](int kt, int half) {  // 1 gload: rows half*64..+63
    char* dst = lds + ((kt & 1) * 49152) + half * 8192;
    gload16(baseA + (size_t)((half * 64) * K + kt * 64), dst + ldst0);
  };
  auto stageB = [&](int kt, int half) {  // 2 gloads: rows half*128..+127
    char* dst = lds + ((kt & 1) * 49152) + 16384 + half * 16384;
#pragma unroll
    for (int q = 0; q < 2; ++q) {
      gload16(baseB + (size_t)((half * 128 + q * 64) * K + kt * 64),
              dst + q * 8192 + ldst0);
    }
  };

  f32x4 acc[4][4] = {};

  // prologue: tile0 {B0,A0,B1,A1} + tile1 {B0,A0}
  stageB(0, 0); stageA(0, 0); stageB(0, 1); stageA(0, 1);
  if (nt > 1) { stageB(1, 0); stageA(1, 0); }

  for (int t = 0; t < nt; ++t) {
    const unsigned po = (unsigned)(t & 1) * 49152u;
    short8 a_[4][2], b_[4][2];

    // ---- p1: publish t; Q1 (mi01 x nj01), 8 reads; stage (t+1).B1 ----
    if (t + 1 < nt) asm volatile("s_waitcnt vmcnt(3)");
    else            asm volatile("s_waitcnt vmcnt(0)");
    BAR();
#pragma unroll
    for (int mi = 0; mi < 2; ++mi) a_[mi][0] = dsr(arow0 + po + (unsigned)(mi * 2048));
#pragma unroll
    for (int nj = 0; nj < 2; ++nj) b_[nj][0] = dsr(brow0 + po + (unsigned)(nj * 2048));
#pragma unroll
    for (int mi = 0; mi < 2; ++mi) a_[mi][1] = dsr((arow0 + po + (unsigned)(mi * 2048)) ^ 64u);
#pragma unroll
    for (int nj = 0; nj < 2; ++nj) b_[nj][1] = dsr((brow0 + po + (unsigned)(nj * 2048)) ^ 64u);
    if (t + 1 < nt) stageB(t + 1, 1);
    asm volatile("s_waitcnt lgkmcnt(4)");
    SB0();
    PRIO(1);
#pragma unroll
    for (int mi = 0; mi < 2; ++mi)
#pragma unroll
      for (int nj = 0; nj < 2; ++nj)
        acc[mi][nj] = MFMA16(a_[mi][0], b_[nj][0], acc[mi][nj]);
    asm volatile("s_waitcnt lgkmcnt(0)");
    SB0();
#pragma unroll
    for (int mi = 0; mi < 2; ++mi)
#pragma unroll
      for (int nj = 0; nj < 2; ++nj)
        acc[mi][nj] = MFMA16(a_[mi][1], b_[nj][1], acc[mi][nj]);
    PRIO(0);

    // ---- p2: Q2 (mi01 x nj23), read b23; stage (t+1).A1 ----
#pragma unroll
    for (int nj = 0; nj < 2; ++nj) {
      unsigned bd = brow0 + po + (unsigned)((nj + 2) * 2048);
      b_[nj + 2][0] = dsr(bd); b_[nj + 2][1] = dsr(bd ^ 64u);
    }
    if (t + 1 < nt) stageA(t + 1, 1);
    BAR();
    asm volatile("s_waitcnt lgkmcnt(0)");
    SB0();
    PRIO(1);
#pragma unroll
    for (int kk = 0; kk < 2; ++kk)
#pragma unroll
      for (int mi = 0; mi < 2; ++mi)
#pragma unroll
        for (int nj = 0; nj < 2; ++nj)
          acc[mi][nj + 2] = MFMA16(a_[mi][kk], b_[nj + 2][kk], acc[mi][nj + 2]);
    PRIO(0);

    // ---- p3: Q3 (mi23 x nj01), read a23; stage (t+2).B0 ----
#pragma unroll
    for (int mi = 0; mi < 2; ++mi) {
      unsigned ad = arow0 + po + (unsigned)((mi + 2) * 2048);
      a_[mi + 2][0] = dsr(ad); a_[mi + 2][1] = dsr(ad ^ 64u);
    }
    BAR();
    if (t + 2 < nt) stageB(t + 2, 0);
    asm volatile("s_waitcnt lgkmcnt(0)");
    SB0();
    PRIO(1);
#pragma unroll
    for (int kk = 0; kk < 2; ++kk)
#pragma unroll
      for (int mi = 0; mi < 2; ++mi)
#pragma unroll
        for (int nj = 0; nj < 2; ++nj)
          acc[mi + 2][nj] = MFMA16(a_[mi + 2][kk], b_[nj][kk], acc[mi + 2][nj]);
    PRIO(0);

    // ---- p4: Q4 (mi23 x nj23); stage (t+2).A0 ----
    BAR();
    if (t + 2 < nt) stageA(t + 2, 0);
    PRIO(1);
#pragma unroll
    for (int kk = 0; kk < 2; ++kk)
#pragma unroll
      for (int mi = 0; mi < 2; ++mi)
#pragma unroll
        for (int nj = 0; nj < 2; ++nj)
          acc[mi + 2][nj + 2] = MFMA16(a_[mi + 2][kk], b_[nj + 2][kk], acc[mi + 2][nj + 2]);
    PRIO(0);
  }

  float biasv[4];
#pragma unroll
  for (int nj = 0; nj < 4; ++nj)
    biasv[nj] = bias[bn + wn * 64 + nj * 16 + ln15];

#pragma unroll
  for (int mi = 0; mi < 4; ++mi) {
    int row0 = bm + wm * 64 + mi * 16 + (lane >> 4) * 4;
#pragma unroll
    for (int nj = 0; nj < 4; ++nj) {
      int col = bn + wn * 64 + nj * 16 + ln15;
#pragma unroll
      for (int r = 0; r < 4; ++r) {
        float v = acc[mi][nj][r] + biasv[nj];
        v = v > 0.f ? v : 0.f;
        size_t idx = (size_t)(row0 + r) * N + col;
        Cb[idx] = __float2bfloat16(v);
        if (Cf) Cf[idx] = v;
      }
    }
  }
}

// ---------------------------------------------------------------------------
// m97-structure 128x128 GEMM (L5 only).
// ---------------------------------------------------------------------------
__global__ __launch_bounds__(256, 2) void gemm_bt(
    const __hip_bfloat16* __restrict__ A,
    const __hip_bfloat16* __restrict__ Bt,
    const float* __restrict__ bias,
    __hip_bfloat16* __restrict__ Cb,
    float* __restrict__ Cf,
    int N, int K) {
  __shared__ char lds[32768];

  const int tid  = threadIdx.x;
  const int lane = tid & 63;
  const int wid  = tid >> 6;
  const int wm   = wid >> 1;
  const int wn   = wid & 1;
  const int bm   = blockIdx.y * 128;
  const int bn   = blockIdx.x * 128;

  f32x4 acc[4][4] = {};

  const int srow = tid >> 3;
  const int sk   = (tid & 7) * 8;
  const int kTiles = K >> 6;

  for (int kt = 0; kt < kTiles; ++kt) {
    __syncthreads();
    const __hip_bfloat16* ga = A  + (size_t)(bm + srow) * K + kt * 64 + sk;
    const __hip_bfloat16* gb = Bt + (size_t)(bn + srow) * K + kt * 64 + sk;
#pragma unroll
    for (int p = 0; p < 4; ++p) {
      gload16(ga + (size_t)(p * 32) * K, &lds[p * 4096 + wid * 1024]);
      gload16(gb + (size_t)(p * 32) * K, &lds[16384 + p * 4096 + wid * 1024]);
    }
    __syncthreads();

#pragma unroll
    for (int kk = 0; kk < 2; ++kk) {
      short8 avec[4], bvec[4];
#pragma unroll
      for (int i = 0; i < 4; ++i) {
        int row = wm * 64 + i * 16 + (lane & 15);
        avec[i] = *(const short8*)&lds[row * 128 + kk * 64 + (lane >> 4) * 16];
      }
#pragma unroll
      for (int j = 0; j < 4; ++j) {
        int row = wn * 64 + j * 16 + (lane & 15);
        bvec[j] = *(const short8*)&lds[16384 + row * 128 + kk * 64 + (lane >> 4) * 16];
      }
#pragma unroll
      for (int i = 0; i < 4; ++i)
#pragma unroll
        for (int j = 0; j < 4; ++j)
          acc[i][j] = MFMA16(avec[i], bvec[j], acc[i][j]);
    }
  }

  float biasv[4];
#pragma unroll
  for (int j = 0; j < 4; ++j)
    biasv[j] = bias[bn + wn * 64 + j * 16 + (lane & 15)];

#pragma unroll
  for (int i = 0; i < 4; ++i) {
    int row0 = bm + wm * 64 + i * 16 + (lane >> 4) * 4;
#pragma unroll
    for (int j = 0; j < 4; ++j) {
      int col = bn + wn * 64 + j * 16 + (lane & 15);
#pragma unroll
      for (int r = 0; r < 4; ++r) {
        float v = acc[i][j][r] + biasv[j];
        v = v > 0.f ? v : 0.f;
        size_t idx = (size_t)(row0 + r) * N + col;
        Cb[idx] = __float2bfloat16(v);
        if (Cf) Cf[idx] = v;
      }
    }
  }
}

// ---------------------------------------------------------------------------
// Head: out[r] = sigmoid( sum(wide[r,:]) + dot(D[r,:], Wh[dom[r],:]) + bh[dom[r]] )
// ---------------------------------------------------------------------------
__global__ __launch_bounds__(256) void head_kernel(
    const float* __restrict__ wide,
    const __hip_bfloat16* __restrict__ D,
    const int* __restrict__ dom,
    const float* __restrict__ Wh,
    const float* __restrict__ bh,
    float* __restrict__ out, int B) {
  const int wid  = threadIdx.x >> 6;
  const int lane = threadIdx.x & 63;
  const int row  = blockIdx.x * 4 + wid;
  if (row >= B) return;
  const int dm = dom[row];

  f32x4 wv = ((const f32x4*)(wide + (size_t)row * 256))[lane];
  float tot = wv[0] + wv[1] + wv[2] + wv[3];

  const unsigned short* drow = (const unsigned short*)(D + (size_t)row * 256);
  ushort4 dv = ((const ushort4*)drow)[lane];
  f32x4 hv = ((const f32x4*)(Wh + (size_t)dm * 256))[lane];
  tot += bf_bits2f(dv.x) * hv[0] + bf_bits2f(dv.y) * hv[1] +
         bf_bits2f(dv.z) * hv[2] + bf_bits2f(dv.w) * hv[3];

#pragma unroll
  for (int off = 32; off > 0; off >>= 1) tot += __shfl_xor(tot, off);

  if (lane == 0) {
    float x = tot + bh[dm];
    out[row] = 1.f / (1.f + __expf(-x));
  }
}

// ---------------------------------------------------------------------------
extern "C" void kernel_launch(void* const* d_in, const int* in_sizes, int n_in,
                              void* d_out, int out_size, void* d_ws, size_t ws_size,
                              hipStream_t stream) {
  const float* wide = (const float*)d_in[0];
  const float* deep = (const float*)d_in[1];
  const int*   dom  = (const int*)d_in[2];
  const float* W1  = (const float*)d_in[3];
  const float* b1  = (const float*)d_in[4];
  const float* W2  = (const float*)d_in[5];
  const float* b2  = (const float*)d_in[6];
  const float* W3  = (const float*)d_in[7];
  const float* b3  = (const float*)d_in[8];
  const float* Wd1 = (const float*)d_in[9];
  const float* bd1 = (const float*)d_in[10];
  const float* Wd2 = (const float*)d_in[11];
  const float* bd2 = (const float*)d_in[12];
  const float* Wh  = (const float*)d_in[13];
  const float* bh  = (const float*)d_in[14];
  float* out = (float*)d_out;

  const int B = 16384;
  char* ws = (char*)d_ws;
  __hip_bfloat16* buf0 = (__hip_bfloat16*)ws;
  __hip_bfloat16* buf1 = (__hip_bfloat16*)(ws + 33554432ull);
  __hip_bfloat16* W1t  = (__hip_bfloat16*)(ws + 100663296ull);
  __hip_bfloat16* W2t  = W1t + 2048 * 1024;
  __hip_bfloat16* W3t  = W2t + 1024 * 2048;
  __hip_bfloat16* Wd1t = W3t + 512 * 1024;
  __hip_bfloat16* Wd2t = Wd1t + 512 * 512;

  transpose_convert<<<dim3(2048 / 64, 1024 / 64), 256, 0, stream>>>(W1, W1t, 1024, 2048);
  transpose_convert<<<dim3(1024 / 64, 2048 / 64), 256, 0, stream>>>(W2, W2t, 2048, 1024);
  transpose_convert<<<dim3(512 / 64, 1024 / 64), 256, 0, stream>>>(W3, W3t, 1024, 512);
  transpose_convert<<<dim3(512 / 64, 512 / 64), 256, 0, stream>>>(Wd1, Wd1t, 512, 512);
  transpose_convert<<<dim3(256 / 64, 512 / 64), 256, 0, stream>>>(Wd2, Wd2t, 512, 256);

  {
    int n8 = B * 1024 / 8;
    f32_to_bf16<<<(n8 + 255) / 256, 256, 0, stream>>>(deep, (unsigned short*)buf0, n8);
  }

  float* shared_out = out + B;
  float* d_out_f    = out + B + (size_t)B * 512;

  // L1: [B,1024]x[1024,2048] -> H1 (buf1)   [R4 schedule = control]
  gemm_8p<<<dim3((2048 / 256) * (B / 256)), 512, 0, stream>>>(
      buf0, W1t, b1, buf1, nullptr, 2048, 1024, 2048 / 256);
  // L2: [B,2048]x[2048,1024] -> H2 (buf0)   [pipelined variant Q]
  gemm_8pq<<<dim3((1024 / 256) * (B / 256)), 512, 0, stream>>>(
      buf1, W2t, b2, buf0, 1024, 2048, 1024 / 256);
  // L3: [B,1024]x[1024,512] -> S (buf1 bf16 + fp32 out)   [gemm_128, 256 blocks]
  gemm_128<<<dim3((B / 128) * (512 / 256)), 512, 0, stream>>>(
      buf0, W3t, b3, buf1, shared_out, 512, 1024, 512 / 256);
  // L4: [B,512]x[512,512] -> T1 (buf0)   [gemm_128, 256 blocks]
  gemm_128<<<dim3((B / 128) * (512 / 256)), 512, 0, stream>>>(
      buf1, Wd1t, bd1, buf0, nullptr, 512, 512, 512 / 256);
  // L5: [B,512]x[512,256] -> D (buf1 bf16 + fp32 out)
  gemm_bt<<<dim3(256 / 128, B / 128), 256, 0, stream>>>(buf0, Wd2t, bd2, buf1, d_out_f, 256, 512);

  head_kernel<<<B / 4, 256, 0, stream>>>(wide, buf1, dom, Wh, bh, out, B);
}

// Round 6
// 224.406 us; speedup vs baseline: 1.3230x; 1.0128x over previous
//
#include <hip/hip_runtime.h>
#include <hip/hip_bf16.h>

// ---------------------------------------------------------------------------
// Wide&Deep forward: 5-layer GEMM chain (bf16 MFMA) + wide-sum + domain head.
// L1/L2: gemm_2b  — 256x256, BK=64, 8 waves, dbuf LDS, 2 barriers/K-tile,
//                   fully read-ahead pipelined (every MFMA gates on ds_reads
//                   issued >=1 phase earlier via counted lgkm).
// L3/L4: gemm_128 — 128x256 variant of the same schedule.
// L5: gemm_bt (m97 structure). + converts + head.
// ---------------------------------------------------------------------------

typedef __attribute__((ext_vector_type(8))) short short8;
typedef __attribute__((ext_vector_type(4))) float f32x4;

static __device__ __forceinline__ unsigned short f2bf_bits(float x) {
  __hip_bfloat16 h = __float2bfloat16(x);
  return __builtin_bit_cast(unsigned short, h);
}
static __device__ __forceinline__ float bf_bits2f(unsigned short u) {
  __hip_bfloat16 h = __builtin_bit_cast(__hip_bfloat16, u);
  return __bfloat162float(h);
}

static __device__ __forceinline__ void gload16(const void* g, void* l) {
  __builtin_amdgcn_global_load_lds(
      (const __attribute__((address_space(1))) void*)g,
      (__attribute__((address_space(3))) void*)l, 16, 0, 0);
}

static __device__ __forceinline__ unsigned lds_u32(const void* p) {
  return (unsigned)(uintptr_t)(const __attribute__((address_space(3))) void*)p;
}

// compiler-invisible LDS read
static __device__ __forceinline__ short8 dsr(unsigned addr) {
  short8 r;
  asm volatile("ds_read_b128 %0, %1" : "=v"(r) : "v"(addr));
  return r;
}

#define MFMA16(a, b, c) __builtin_amdgcn_mfma_f32_16x16x32_bf16((a), (b), (c), 0, 0, 0)
#define SB0() __builtin_amdgcn_sched_barrier(0)
#define PRIO(x) __builtin_amdgcn_s_setprio(x)
#define BAR() __builtin_amdgcn_s_barrier()

// ---------------------------------------------------------------------------
// Transpose-convert: W [K][N] f32 -> Wt [N][K] bf16
// ---------------------------------------------------------------------------
__global__ void transpose_convert(const float* __restrict__ W,
                                  __hip_bfloat16* __restrict__ Wt,
                                  int K, int N) {
  __shared__ float tile[64][65];
  const int k0 = blockIdx.y * 64;
  const int n0 = blockIdx.x * 64;
  const int t  = threadIdx.x;
  const int tn = t & 63;
  const int t4 = t >> 6;
#pragma unroll
  for (int p = 0; p < 16; ++p) {
    int kl = p * 4 + t4;
    tile[kl][tn] = W[(size_t)(k0 + kl) * N + (n0 + tn)];
  }
  __syncthreads();
#pragma unroll
  for (int p = 0; p < 16; ++p) {
    int nl = p * 4 + t4;
    Wt[(size_t)(n0 + nl) * K + (k0 + tn)] = __float2bfloat16(tile[tn][nl]);
  }
}

// ---------------------------------------------------------------------------
// f32 -> bf16 bulk convert
// ---------------------------------------------------------------------------
__global__ void f32_to_bf16(const float* __restrict__ in,
                            unsigned short* __restrict__ out, int n8) {
  int i = blockIdx.x * blockDim.x + threadIdx.x;
  if (i >= n8) return;
  const f32x4* p = (const f32x4*)in + (size_t)i * 2;
  f32x4 a = p[0], b = p[1];
  short8 o;
  o[0] = (short)f2bf_bits(a[0]); o[1] = (short)f2bf_bits(a[1]);
  o[2] = (short)f2bf_bits(a[2]); o[3] = (short)f2bf_bits(a[3]);
  o[4] = (short)f2bf_bits(b[0]); o[5] = (short)f2bf_bits(b[1]);
  o[6] = (short)f2bf_bits(b[2]); o[7] = (short)f2bf_bits(b[3]);
  *(short8*)(out + (size_t)i * 8) = o;
}

// ---------------------------------------------------------------------------
// gemm_2b: 256x256, BK=64, 8 waves 2x4, 2 barriers/K-tile.
// Phases (per tile t):
//  P1: lgkm0(aLo); read b0,b1; stage(t+1).B1; lgkm(6)->Q1kk0; lgkm(4)->Q1kk1
//  P2: read aHi; stage(t+1).A1; lgkm(8)->Q2; BARRIER
//  P3: lgkm0(aHi)->Q3; stage(t+2).B0; vmcnt(2)[publish t+1]; BARRIER
//  P4: read aLo(t+1); Q4; stage(t+2).A0
// Hazards: other-buf stages (P1/P2) are >=1 barrier past t-1 read drains;
// cur-buf stages (P3/P4) covered by P2-end barrier (b0/aLo retired at P1
// gates); publish vmcnt(2) retires exactly tile t+1's 8 loads (queue proof).
// ---------------------------------------------------------------------------
__global__ __launch_bounds__(512, 2) void gemm_2b(
    const __hip_bfloat16* __restrict__ A,
    const __hip_bfloat16* __restrict__ Bt,
    const float* __restrict__ bias,
    __hip_bfloat16* __restrict__ Cb,
    float* __restrict__ Cf,
    int N, int K, int nbx) {
  __shared__ char lds[131072];

  const int tid  = threadIdx.x;
  const int lane = tid & 63;
  const int wid  = tid >> 6;
  const int wm   = wid >> 2;
  const int wn   = wid & 3;

  const int nwg = gridDim.x;
  const int cpx = nwg >> 3;
  const int id  = blockIdx.x;
  const int swz = (id & 7) * cpx + (id >> 3);
  const int bm  = (swz / nbx) * 256;
  const int bn  = (swz % nbx) * 256;

  const int ln15 = lane & 15;
  const unsigned cswz = (unsigned)((((lane >> 4) ^ (lane & 7)) << 4));

  const unsigned lbase = lds_u32(lds);
  const unsigned arow0 = lbase + (unsigned)(wm * 128 + ln15) * 128u + cswz;
  const unsigned brow0 = lbase + 32768u + (unsigned)(wn * 64 + ln15) * 128u + cswz;

  const int nt = K >> 6;

  const int swc = (tid & 7) ^ ((tid >> 3) & 7);
  const __hip_bfloat16* baseA = A  + (size_t)(bm + (tid >> 3)) * K + swc * 8;
  const __hip_bfloat16* baseB = Bt + (size_t)(bn + (tid >> 3)) * K + swc * 8;
  const unsigned ldst0 = (unsigned)(wid * 1024);

  auto stage = [&](int kt, int half, int isB) {
    const __hip_bfloat16* base = isB ? baseB : baseA;
    char* dst = lds + ((kt & 1) * 65536) + (isB ? 32768 : 0) + half * 16384;
#pragma unroll
    for (int q = 0; q < 2; ++q) {
      gload16(base + (size_t)((half * 128 + q * 64) * K + kt * 64),
              dst + q * 8192 + ldst0);
    }
  };

  f32x4 acc[8][4] = {};
  short8 aLo[4][2], aHi[4][2], b0v[2][2], b1v[2][2];

  // prologue: tile0 {B0,A0,B1,A1}, tile1 {B0,A0}; publish tile0; read aLo(0)
  stage(0, 0, 1); stage(0, 0, 0); stage(0, 1, 1); stage(0, 1, 0);
  if (nt > 1) {
    stage(1, 0, 1); stage(1, 0, 0);
    asm volatile("s_waitcnt vmcnt(4)");
  } else {
    asm volatile("s_waitcnt vmcnt(0)");
  }
  BAR();
#pragma unroll
  for (int mi = 0; mi < 4; ++mi) {
    unsigned ad = arow0 + (unsigned)(mi * 2048);
    aLo[mi][0] = dsr(ad); aLo[mi][1] = dsr(ad ^ 64u);
  }

  for (int t = 0; t < nt; ++t) {
    const unsigned po = (unsigned)(t & 1) * 65536u;
    const unsigned pn = po ^ 65536u;

    // ---- P1 ----
    asm volatile("s_waitcnt lgkmcnt(0)");  // aLo(t) resident
    SB0();
#pragma unroll
    for (int nj = 0; nj < 2; ++nj) b0v[nj][0] = dsr(brow0 + po + (unsigned)(nj * 2048));
#pragma unroll
    for (int nj = 0; nj < 2; ++nj) b0v[nj][1] = dsr((brow0 + po + (unsigned)(nj * 2048)) ^ 64u);
#pragma unroll
    for (int nj = 0; nj < 2; ++nj) b1v[nj][0] = dsr(brow0 + po + (unsigned)((nj + 2) * 2048));
#pragma unroll
    for (int nj = 0; nj < 2; ++nj) b1v[nj][1] = dsr((brow0 + po + (unsigned)((nj + 2) * 2048)) ^ 64u);
    if (t + 1 < nt) stage(t + 1, 1, 1);
    asm volatile("s_waitcnt lgkmcnt(6)");  // b0 kk0 resident
    SB0();
    PRIO(1);
#pragma unroll
    for (int mi = 0; mi < 4; ++mi)
#pragma unroll
      for (int nj = 0; nj < 2; ++nj)
        acc[mi][nj] = MFMA16(aLo[mi][0], b0v[nj][0], acc[mi][nj]);
    asm volatile("s_waitcnt lgkmcnt(4)");  // b0 kk1 resident
    SB0();
#pragma unroll
    for (int mi = 0; mi < 4; ++mi)
#pragma unroll
      for (int nj = 0; nj < 2; ++nj)
        acc[mi][nj] = MFMA16(aLo[mi][1], b0v[nj][1], acc[mi][nj]);
    PRIO(0);

    // ---- P2 ----
#pragma unroll
    for (int mi = 0; mi < 4; ++mi) {
      unsigned ad = arow0 + po + (unsigned)((mi + 4) * 2048);
      aHi[mi][0] = dsr(ad); aHi[mi][1] = dsr(ad ^ 64u);
    }
    if (t + 1 < nt) stage(t + 1, 1, 0);
    asm volatile("s_waitcnt lgkmcnt(8)");  // b1 resident (aHi 8 outstanding)
    SB0();
    PRIO(1);
#pragma unroll
    for (int kk = 0; kk < 2; ++kk)
#pragma unroll
      for (int mi = 0; mi < 4; ++mi)
#pragma unroll
        for (int nj = 0; nj < 2; ++nj)
          acc[mi][nj + 2] = MFMA16(aLo[mi][kk], b1v[nj][kk], acc[mi][nj + 2]);
    PRIO(0);
    BAR();  // certifies all waves' b0/aLo(t) retired -> cur-buf stages OK

    // ---- P3 ----
    asm volatile("s_waitcnt lgkmcnt(0)");  // aHi resident
    SB0();
    PRIO(1);
#pragma unroll
    for (int kk = 0; kk < 2; ++kk)
#pragma unroll
      for (int mi = 0; mi < 4; ++mi)
#pragma unroll
        for (int nj = 0; nj < 2; ++nj)
          acc[mi + 4][nj] = MFMA16(aHi[mi][kk], b0v[nj][kk], acc[mi + 4][nj]);
    PRIO(0);
    if (t + 2 < nt) stage(t + 2, 0, 1);
    if (t + 2 < nt)      asm volatile("s_waitcnt vmcnt(2)");
    else if (t + 1 < nt) asm volatile("s_waitcnt vmcnt(0)");
    if (t + 1 < nt) BAR();  // publish tile t+1

    // ---- P4 ----
    if (t + 1 < nt) {
#pragma unroll
      for (int mi = 0; mi < 4; ++mi) {
        unsigned ad = arow0 + pn + (unsigned)(mi * 2048);
        aLo[mi][0] = dsr(ad); aLo[mi][1] = dsr(ad ^ 64u);
      }
    }
    SB0();
    PRIO(1);
#pragma unroll
    for (int kk = 0; kk < 2; ++kk)
#pragma unroll
      for (int mi = 0; mi < 4; ++mi)
#pragma unroll
        for (int nj = 0; nj < 2; ++nj)
          acc[mi + 4][nj + 2] = MFMA16(aHi[mi][kk], b1v[nj][kk], acc[mi + 4][nj + 2]);
    PRIO(0);
    if (t + 2 < nt) stage(t + 2, 0, 0);
  }

  float biasv[4];
#pragma unroll
  for (int nj = 0; nj < 4; ++nj)
    biasv[nj] = bias[bn + wn * 64 + nj * 16 + ln15];

#pragma unroll
  for (int mi = 0; mi < 8; ++mi) {
    int row0 = bm + wm * 128 + mi * 16 + (lane >> 4) * 4;
#pragma unroll
    for (int nj = 0; nj < 4; ++nj) {
      int col = bn + wn * 64 + nj * 16 + ln15;
#pragma unroll
      for (int r = 0; r < 4; ++r) {
        float v = acc[mi][nj][r] + biasv[nj];
        v = v > 0.f ? v : 0.f;
        size_t idx = (size_t)(row0 + r) * N + col;
        Cb[idx] = __float2bfloat16(v);
        if (Cf) Cf[idx] = v;
      }
    }
  }
}

// ---------------------------------------------------------------------------
// gemm_128: 128x256, BK=64, 8 waves 2x4 (wave tile 64x64), same 2-barrier
// schedule. Loads/tile = 6 (B halves 2 loads, A halves 1). Publish vmcnt(2)
// retires 6 oldest = tile t+1; prologue vmcnt(3) retires tile 0's 6.
// ---------------------------------------------------------------------------
__global__ __launch_bounds__(512, 2) void gemm_128(
    const __hip_bfloat16* __restrict__ A,
    const __hip_bfloat16* __restrict__ Bt,
    const float* __restrict__ bias,
    __hip_bfloat16* __restrict__ Cb,
    float* __restrict__ Cf,
    int N, int K, int nbx) {
  __shared__ char lds[98304];

  const int tid  = threadIdx.x;
  const int lane = tid & 63;
  const int wid  = tid >> 6;
  const int wm   = wid >> 2;
  const int wn   = wid & 3;

  const int nwg = gridDim.x;
  const int cpx = nwg >> 3;
  const int id  = blockIdx.x;
  const int swz = (id & 7) * cpx + (id >> 3);
  const int bm  = (swz / nbx) * 128;
  const int bn  = (swz % nbx) * 256;

  const int ln15 = lane & 15;
  const unsigned cswz = (unsigned)((((lane >> 4) ^ (lane & 7)) << 4));

  const unsigned lbase = lds_u32(lds);
  const unsigned arow0 = lbase + (unsigned)(wm * 64 + ln15) * 128u + cswz;
  const unsigned brow0 = lbase + 16384u + (unsigned)(wn * 64 + ln15) * 128u + cswz;

  const int nt = K >> 6;

  const int swc = (tid & 7) ^ ((tid >> 3) & 7);
  const __hip_bfloat16* baseA = A  + (size_t)(bm + (tid >> 3)) * K + swc * 8;
  const __hip_bfloat16* baseB = Bt + (size_t)(bn + (tid >> 3)) * K + swc * 8;
  const unsigned ldst0 = (unsigned)(tid * 16);

  auto stageA = [&](int kt, int half) {
    char* dst = lds + ((kt & 1) * 49152) + half * 8192;
    gload16(baseA + (size_t)((half * 64) * K + kt * 64), dst + ldst0);
  };
  auto stageB = [&](int kt, int half) {
    char* dst = lds + ((kt & 1) * 49152) + 16384 + half * 16384;
#pragma unroll
    for (int q = 0; q < 2; ++q) {
      gload16(baseB + (size_t)((half * 128 + q * 64) * K + kt * 64),
              dst + q * 8192 + ldst0);
    }
  };

  f32x4 acc[4][4] = {};
  short8 aLo[2][2], aHi[2][2], b0v[2][2], b1v[2][2];

  // prologue
  stageB(0, 0); stageA(0, 0); stageB(0, 1); stageA(0, 1);
  if (nt > 1) {
    stageB(1, 0); stageA(1, 0);
    asm volatile("s_waitcnt vmcnt(3)");
  } else {
    asm volatile("s_waitcnt vmcnt(0)");
  }
  BAR();
#pragma unroll
  for (int mi = 0; mi < 2; ++mi) {
    unsigned ad = arow0 + (unsigned)(mi * 2048);
    aLo[mi][0] = dsr(ad); aLo[mi][1] = dsr(ad ^ 64u);
  }

  for (int t = 0; t < nt; ++t) {
    const unsigned po = (unsigned)(t & 1) * 49152u;
    const unsigned pn = po ^ 49152u;

    // ---- P1 ----
    asm volatile("s_waitcnt lgkmcnt(0)");
    SB0();
#pragma unroll
    for (int nj = 0; nj < 2; ++nj) b0v[nj][0] = dsr(brow0 + po + (unsigned)(nj * 2048));
#pragma unroll
    for (int nj = 0; nj < 2; ++nj) b0v[nj][1] = dsr((brow0 + po + (unsigned)(nj * 2048)) ^ 64u);
#pragma unroll
    for (int nj = 0; nj < 2; ++nj) b1v[nj][0] = dsr(brow0 + po + (unsigned)((nj + 2) * 2048));
#pragma unroll
    for (int nj = 0; nj < 2; ++nj) b1v[nj][1] = dsr((brow0 + po + (unsigned)((nj + 2) * 2048)) ^ 64u);
    if (t + 1 < nt) stageB(t + 1, 1);
    asm volatile("s_waitcnt lgkmcnt(6)");
    SB0();
    PRIO(1);
#pragma unroll
    for (int mi = 0; mi < 2; ++mi)
#pragma unroll
      for (int nj = 0; nj < 2; ++nj)
        acc[mi][nj] = MFMA16(aLo[mi][0], b0v[nj][0], acc[mi][nj]);
    asm volatile("s_waitcnt lgkmcnt(4)");
    SB0();
#pragma unroll
    for (int mi = 0; mi < 2; ++mi)
#pragma unroll
      for (int nj = 0; nj < 2; ++nj)
        acc[mi][nj] = MFMA16(aLo[mi][1], b0v[nj][1], acc[mi][nj]);
    PRIO(0);

    // ---- P2 ----
#pragma unroll
    for (int mi = 0; mi < 2; ++mi) {
      unsigned ad = arow0 + po + (unsigned)((mi + 2) * 2048);
      aHi[mi][0] = dsr(ad); aHi[mi][1] = dsr(ad ^ 64u);
    }
    if (t + 1 < nt) stageA(t + 1, 1);
    asm volatile("s_waitcnt lgkmcnt(4)");  // b1 resident (aHi 4 outstanding)
    SB0();
    PRIO(1);
#pragma unroll
    for (int kk = 0; kk < 2; ++kk)
#pragma unroll
      for (int mi = 0; mi < 2; ++mi)
#pragma unroll
        for (int nj = 0; nj < 2; ++nj)
          acc[mi][nj + 2] = MFMA16(aLo[mi][kk], b1v[nj][kk], acc[mi][nj + 2]);
    PRIO(0);
    BAR();

    // ---- P3 ----
    asm volatile("s_waitcnt lgkmcnt(0)");
    SB0();
    PRIO(1);
#pragma unroll
    for (int kk = 0; kk < 2; ++kk)
#pragma unroll
      for (int mi = 0; mi < 2; ++mi)
#pragma unroll
        for (int nj = 0; nj < 2; ++nj)
          acc[mi + 2][nj] = MFMA16(aHi[mi][kk], b0v[nj][kk], acc[mi + 2][nj]);
    PRIO(0);
    if (t + 2 < nt) stageB(t + 2, 0);
    if (t + 2 < nt)      asm volatile("s_waitcnt vmcnt(2)");
    else if (t + 1 < nt) asm volatile("s_waitcnt vmcnt(0)");
    if (t + 1 < nt) BAR();

    // ---- P4 ----
    if (t + 1 < nt) {
#pragma unroll
      for (int mi = 0; mi < 2; ++mi) {
        unsigned ad = arow0 + pn + (unsigned)(mi * 2048);
        aLo[mi][0] = dsr(ad); aLo[mi][1] = dsr(ad ^ 64u);
      }
    }
    SB0();
    PRIO(1);
#pragma unroll
    for (int kk = 0; kk < 2; ++kk)
#pragma unroll
      for (int mi = 0; mi < 2; ++mi)
#pragma unroll
        for (int nj = 0; nj < 2; ++nj)
          acc[mi + 2][nj + 2] = MFMA16(aHi[mi][kk], b1v[nj][kk], acc[mi + 2][nj + 2]);
    PRIO(0);
    if (t + 2 < nt) stageA(t + 2, 0);
  }

  float biasv[4];
#pragma unroll
  for (int nj = 0; nj < 4; ++nj)
    biasv[nj] = bias[bn + wn * 64 + nj * 16 + ln15];

#pragma unroll
  for (int mi = 0; mi < 4; ++mi) {
    int row0 = bm + wm * 64 + mi * 16 + (lane >> 4) * 4;
#pragma unroll
    for (int nj = 0; nj < 4; ++nj) {
      int col = bn + wn * 64 + nj * 16 + ln15;
#pragma unroll
      for (int r = 0; r < 4; ++r) {
        float v = acc[mi][nj][r] + biasv[nj];
        v = v > 0.f ? v : 0.f;
        size_t idx = (size_t)(row0 + r) * N + col;
        Cb[idx] = __float2bfloat16(v);
        if (Cf) Cf[idx] = v;
      }
    }
  }
}

// ---------------------------------------------------------------------------
// m97-structure 128x128 GEMM (L5 only).
// ---------------------------------------------------------------------------
__global__ __launch_bounds__(256, 2) void gemm_bt(
    const __hip_bfloat16* __restrict__ A,
    const __hip_bfloat16* __restrict__ Bt,
    const float* __restrict__ bias,
    __hip_bfloat16* __restrict__ Cb,
    float* __restrict__ Cf,
    int N, int K) {
  __shared__ char lds[32768];

  const int tid  = threadIdx.x;
  const int lane = tid & 63;
  const int wid  = tid >> 6;
  const int wm   = wid >> 1;
  const int wn   = wid & 1;
  const int bm   = blockIdx.y * 128;
  const int bn   = blockIdx.x * 128;

  f32x4 acc[4][4] = {};

  const int srow = tid >> 3;
  const int sk   = (tid & 7) * 8;
  const int kTiles = K >> 6;

  for (int kt = 0; kt < kTiles; ++kt) {
    __syncthreads();
    const __hip_bfloat16* ga = A  + (size_t)(bm + srow) * K + kt * 64 + sk;
    const __hip_bfloat16* gb = Bt + (size_t)(bn + srow) * K + kt * 64 + sk;
#pragma unroll
    for (int p = 0; p < 4; ++p) {
      gload16(ga + (size_t)(p * 32) * K, &lds[p * 4096 + wid * 1024]);
      gload16(gb + (size_t)(p * 32) * K, &lds[16384 + p * 4096 + wid * 1024]);
    }
    __syncthreads();

#pragma unroll
    for (int kk = 0; kk < 2; ++kk) {
      short8 avec[4], bvec[4];
#pragma unroll
      for (int i = 0; i < 4; ++i) {
        int row = wm * 64 + i * 16 + (lane & 15);
        avec[i] = *(const short8*)&lds[row * 128 + kk * 64 + (lane >> 4) * 16];
      }
#pragma unroll
      for (int j = 0; j < 4; ++j) {
        int row = wn * 64 + j * 16 + (lane & 15);
        bvec[j] = *(const short8*)&lds[16384 + row * 128 + kk * 64 + (lane >> 4) * 16];
      }
#pragma unroll
      for (int i = 0; i < 4; ++i)
#pragma unroll
        for (int j = 0; j < 4; ++j)
          acc[i][j] = MFMA16(avec[i], bvec[j], acc[i][j]);
    }
  }

  float biasv[4];
#pragma unroll
  for (int j = 0; j < 4; ++j)
    biasv[j] = bias[bn + wn * 64 + j * 16 + (lane & 15)];

#pragma unroll
  for (int i = 0; i < 4; ++i) {
    int row0 = bm + wm * 64 + i * 16 + (lane >> 4) * 4;
#pragma unroll
    for (int j = 0; j < 4; ++j) {
      int col = bn + wn * 64 + j * 16 + (lane & 15);
#pragma unroll
      for (int r = 0; r < 4; ++r) {
        float v = acc[i][j][r] + biasv[j];
        v = v > 0.f ? v : 0.f;
        size_t idx = (size_t)(row0 + r) * N + col;
        Cb[idx] = __float2bfloat16(v);
        if (Cf) Cf[idx] = v;
      }
    }
  }
}

// ---------------------------------------------------------------------------
// Head: out[r] = sigmoid( sum(wide[r,:]) + dot(D[r,:], Wh[dom[r],:]) + bh[dom[r]] )
// ---------------------------------------------------------------------------
__global__ __launch_bounds__(256) void head_kernel(
    const float* __restrict__ wide,
    const __hip_bfloat16* __restrict__ D,
    const int* __restrict__ dom,
    const float* __restrict__ Wh,
    const float* __restrict__ bh,
    float* __restrict__ out, int B) {
  const int wid  = threadIdx.x >> 6;
  const int lane = threadIdx.x & 63;
  const int row  = blockIdx.x * 4 + wid;
  if (row >= B) return;
  const int dm = dom[row];

  f32x4 wv = ((const f32x4*)(wide + (size_t)row * 256))[lane];
  float tot = wv[0] + wv[1] + wv[2] + wv[3];

  const unsigned short* drow = (const unsigned short*)(D + (size_t)row * 256);
  ushort4 dv = ((const ushort4*)drow)[lane];
  f32x4 hv = ((const f32x4*)(Wh + (size_t)dm * 256))[lane];
  tot += bf_bits2f(dv.x) * hv[0] + bf_bits2f(dv.y) * hv[1] +
         bf_bits2f(dv.z) * hv[2] + bf_bits2f(dv.w) * hv[3];

#pragma unroll
  for (int off = 32; off > 0; off >>= 1) tot += __shfl_xor(tot, off);

  if (lane == 0) {
    float x = tot + bh[dm];
    out[row] = 1.f / (1.f + __expf(-x));
  }
}

// ---------------------------------------------------------------------------
extern "C" void kernel_launch(void* const* d_in, const int* in_sizes, int n_in,
                              void* d_out, int out_size, void* d_ws, size_t ws_size,
                              hipStream_t stream) {
  const float* wide = (const float*)d_in[0];
  const float* deep = (const float*)d_in[1];
  const int*   dom  = (const int*)d_in[2];
  const float* W1  = (const float*)d_in[3];
  const float* b1  = (const float*)d_in[4];
  const float* W2  = (const float*)d_in[5];
  const float* b2  = (const float*)d_in[6];
  const float* W3  = (const float*)d_in[7];
  const float* b3  = (const float*)d_in[8];
  const float* Wd1 = (const float*)d_in[9];
  const float* bd1 = (const float*)d_in[10];
  const float* Wd2 = (const float*)d_in[11];
  const float* bd2 = (const float*)d_in[12];
  const float* Wh  = (const float*)d_in[13];
  const float* bh  = (const float*)d_in[14];
  float* out = (float*)d_out;

  const int B = 16384;
  char* ws = (char*)d_ws;
  __hip_bfloat16* buf0 = (__hip_bfloat16*)ws;
  __hip_bfloat16* buf1 = (__hip_bfloat16*)(ws + 33554432ull);
  __hip_bfloat16* W1t  = (__hip_bfloat16*)(ws + 100663296ull);
  __hip_bfloat16* W2t  = W1t + 2048 * 1024;
  __hip_bfloat16* W3t  = W2t + 1024 * 2048;
  __hip_bfloat16* Wd1t = W3t + 512 * 1024;
  __hip_bfloat16* Wd2t = Wd1t + 512 * 512;

  transpose_convert<<<dim3(2048 / 64, 1024 / 64), 256, 0, stream>>>(W1, W1t, 1024, 2048);
  transpose_convert<<<dim3(1024 / 64, 2048 / 64), 256, 0, stream>>>(W2, W2t, 2048, 1024);
  transpose_convert<<<dim3(512 / 64, 1024 / 64), 256, 0, stream>>>(W3, W3t, 1024, 512);
  transpose_convert<<<dim3(512 / 64, 512 / 64), 256, 0, stream>>>(Wd1, Wd1t, 512, 512);
  transpose_convert<<<dim3(256 / 64, 512 / 64), 256, 0, stream>>>(Wd2, Wd2t, 512, 256);

  {
    int n8 = B * 1024 / 8;
    f32_to_bf16<<<(n8 + 255) / 256, 256, 0, stream>>>(deep, (unsigned short*)buf0, n8);
  }

  float* shared_out = out + B;
  float* d_out_f    = out + B + (size_t)B * 512;

  // L1: [B,1024]x[1024,2048] -> H1 (buf1)
  gemm_2b<<<dim3((2048 / 256) * (B / 256)), 512, 0, stream>>>(
      buf0, W1t, b1, buf1, nullptr, 2048, 1024, 2048 / 256);
  // L2: [B,2048]x[2048,1024] -> H2 (buf0)
  gemm_2b<<<dim3((1024 / 256) * (B / 256)), 512, 0, stream>>>(
      buf1, W2t, b2, buf0, nullptr, 1024, 2048, 1024 / 256);
  // L3: [B,1024]x[1024,512] -> S (buf1 bf16 + fp32 out)
  gemm_128<<<dim3((B / 128) * (512 / 256)), 512, 0, stream>>>(
      buf0, W3t, b3, buf1, shared_out, 512, 1024, 512 / 256);
  // L4: [B,512]x[512,512] -> T1 (buf0)
  gemm_128<<<dim3((B / 128) * (512 / 256)), 512, 0, stream>>>(
      buf1, Wd1t, bd1, buf0, nullptr, 512, 512, 512 / 256);
  // L5: [B,512]x[512,256] -> D (buf1 bf16 + fp32 out)
  gemm_bt<<<dim3(256 / 128, B / 128), 256, 0, stream>>>(buf0, Wd2t, bd2, buf1, d_out_f, 256, 512);

  head_kernel<<<B / 4, 256, 0, stream>>>(wide, buf1, dom, Wh, bh, out, B);
}

// Round 7
// 224.278 us; speedup vs baseline: 1.3237x; 1.0006x over previous
//
#include <hip/hip_runtime.h>
#include <hip/hip_bf16.h>

// ---------------------------------------------------------------------------
// Wide&Deep forward: 5-layer GEMM chain (bf16 MFMA) + wide-sum + domain head.
// L1/L2: gemm_2c — 256x256, BK=64, 8 waves, dbuf LDS, 2 barriers/K-tile,
//   compiler-visible LDS reads issued >=1 MFMA-cluster before use; only
//   counted vmcnt in asm (publish); compiler free to interleave.
// L3/L4: gemm_128 (R6). L5: gemm_bt (m97). + converts + head.
// ---------------------------------------------------------------------------

typedef __attribute__((ext_vector_type(8))) short short8;
typedef __attribute__((ext_vector_type(4))) float f32x4;

static __device__ __forceinline__ unsigned short f2bf_bits(float x) {
  __hip_bfloat16 h = __float2bfloat16(x);
  return __builtin_bit_cast(unsigned short, h);
}
static __device__ __forceinline__ float bf_bits2f(unsigned short u) {
  __hip_bfloat16 h = __builtin_bit_cast(__hip_bfloat16, u);
  return __bfloat162float(h);
}

static __device__ __forceinline__ void gload16(const void* g, void* l) {
  __builtin_amdgcn_global_load_lds(
      (const __attribute__((address_space(1))) void*)g,
      (__attribute__((address_space(3))) void*)l, 16, 0, 0);
}

static __device__ __forceinline__ unsigned lds_u32(const void* p) {
  return (unsigned)(uintptr_t)(const __attribute__((address_space(3))) void*)p;
}

// compiler-invisible LDS read (kept for gemm_128/R6 path)
static __device__ __forceinline__ short8 dsr(unsigned addr) {
  short8 r;
  asm volatile("ds_read_b128 %0, %1" : "=v"(r) : "v"(addr));
  return r;
}

#define MFMA16(a, b, c) __builtin_amdgcn_mfma_f32_16x16x32_bf16((a), (b), (c), 0, 0, 0)
#define SB0() __builtin_amdgcn_sched_barrier(0)
#define PRIO(x) __builtin_amdgcn_s_setprio(x)
#define BAR() __builtin_amdgcn_s_barrier()
#define MEMFENCE() asm volatile("" ::: "memory")

// ---------------------------------------------------------------------------
// Transpose-convert: W [K][N] f32 -> Wt [N][K] bf16
// ---------------------------------------------------------------------------
__global__ void transpose_convert(const float* __restrict__ W,
                                  __hip_bfloat16* __restrict__ Wt,
                                  int K, int N) {
  __shared__ float tile[64][65];
  const int k0 = blockIdx.y * 64;
  const int n0 = blockIdx.x * 64;
  const int t  = threadIdx.x;
  const int tn = t & 63;
  const int t4 = t >> 6;
#pragma unroll
  for (int p = 0; p < 16; ++p) {
    int kl = p * 4 + t4;
    tile[kl][tn] = W[(size_t)(k0 + kl) * N + (n0 + tn)];
  }
  __syncthreads();
#pragma unroll
  for (int p = 0; p < 16; ++p) {
    int nl = p * 4 + t4;
    Wt[(size_t)(n0 + nl) * K + (k0 + tn)] = __float2bfloat16(tile[tn][nl]);
  }
}

// ---------------------------------------------------------------------------
// f32 -> bf16 bulk convert
// ---------------------------------------------------------------------------
__global__ void f32_to_bf16(const float* __restrict__ in,
                            unsigned short* __restrict__ out, int n8) {
  int i = blockIdx.x * blockDim.x + threadIdx.x;
  if (i >= n8) return;
  const f32x4* p = (const f32x4*)in + (size_t)i * 2;
  f32x4 a = p[0], b = p[1];
  short8 o;
  o[0] = (short)f2bf_bits(a[0]); o[1] = (short)f2bf_bits(a[1]);
  o[2] = (short)f2bf_bits(a[2]); o[3] = (short)f2bf_bits(a[3]);
  o[4] = (short)f2bf_bits(b[0]); o[5] = (short)f2bf_bits(b[1]);
  o[6] = (short)f2bf_bits(b[2]); o[7] = (short)f2bf_bits(b[3]);
  *(short8*)(out + (size_t)i * 8) = o;
}

// ---------------------------------------------------------------------------
// gemm_2c: 256x256, BK=64, 8 waves 2x4, 2 barriers/K-tile, compiler-visible
// LDS reads with >=1-cluster issue-to-use distance.
// Per tile t:
//  P1: read b1(t); stage(t+1).B1; Q1 = aLo x b0 (operands read in P4(t-1))
//  P2: read aHi(t); stage(t+1).A1; Q2 = aLo x b1; BARRIER-A
//  P3: Q3 = aHi x b0; stage(t+2).B0; vmcnt(2) publish t+1; BARRIER-B
//  P4: read aLo,b0(t+1) [post-publish]; Q4 = aHi x b1; stage(t+2).A0
// WAR ledger: stage(t+1).B1@P1 region last-read by b1(t-1) [retired < Q2(t-1)
// < BAR-A(t-1) < P1(t)]; stage(t+1).A1@P2 ~ aHi(t-1) [< Q3 < BAR-B(t-1)];
// stage(t+2).B0@P3 ~ b0(t) ds_reads [retired < Q1(t) < BAR-A(t)];
// stage(t+2).A0@P4 ~ aLo(t) [same]. RAW: vmcnt(2)@P3 retires all 8 loads of
// tile t+1 (queue: B0,A0@P3/P4(t-1) retired by prior publishes; outstanding
// B1,A1(t+1)@P1,P2(t) + B0(t+2)@P3(t) = 6 -> wait 2 leaves B0(t+2)).
// ---------------------------------------------------------------------------
__global__ __launch_bounds__(512, 2) void gemm_2c(
    const __hip_bfloat16* __restrict__ A,
    const __hip_bfloat16* __restrict__ Bt,
    const float* __restrict__ bias,
    __hip_bfloat16* __restrict__ Cb,
    float* __restrict__ Cf,
    int N, int K, int nbx) {
  __shared__ char lds[131072];

  const int tid  = threadIdx.x;
  const int lane = tid & 63;
  const int wid  = tid >> 6;
  const int wm   = wid >> 2;
  const int wn   = wid & 3;

  const int nwg = gridDim.x;
  const int cpx = nwg >> 3;
  const int id  = blockIdx.x;
  const int swz = (id & 7) * cpx + (id >> 3);
  const int bm  = (swz / nbx) * 256;
  const int bn  = (swz % nbx) * 256;

  const int ln15 = lane & 15;
  const unsigned cswz = (unsigned)((((lane >> 4) ^ (lane & 7)) << 4));

  const unsigned aoff = (unsigned)((wm * 128 + ln15) * 128) + cswz;
  const unsigned boff = 32768u + (unsigned)((wn * 64 + ln15) * 128) + cswz;

  const int nt = K >> 6;

  const __hip_bfloat16* baseA = A  + (size_t)(bm + (tid >> 3)) * K +
                                ((tid & 7) ^ ((tid >> 3) & 7)) * 8;
  const __hip_bfloat16* baseB = Bt + (size_t)(bn + (tid >> 3)) * K +
                                ((tid & 7) ^ ((tid >> 3) & 7)) * 8;
  const unsigned ldst0 = (unsigned)(wid * 1024);

  auto stage = [&](int kt, int half, int isB) {
    const __hip_bfloat16* base = isB ? baseB : baseA;
    char* dst = lds + ((kt & 1) * 65536) + (isB ? 32768 : 0) + half * 16384;
#pragma unroll
    for (int q = 0; q < 2; ++q) {
      gload16(base + (size_t)((half * 128 + q * 64) * K + kt * 64),
              dst + q * 8192 + ldst0);
    }
  };

  auto LD = [&](unsigned off) -> short8 {
    return *(const short8*)&lds[off];
  };

  f32x4 acc[8][4] = {};
  short8 aLo[4][2], aHi[4][2], b0v[2][2], b1v[2][2];

  // prologue: tile0 {B0,A0,B1,A1}, tile1 {B0,A0}; publish tile0
  stage(0, 0, 1); stage(0, 0, 0); stage(0, 1, 1); stage(0, 1, 0);
  if (nt > 1) {
    stage(1, 0, 1); stage(1, 0, 0);
    asm volatile("s_waitcnt vmcnt(4)");
  } else {
    asm volatile("s_waitcnt vmcnt(0)");
  }
  BAR();
  MEMFENCE();
  // initial reads: aLo(0), b0(0)
#pragma unroll
  for (int mi = 0; mi < 4; ++mi)
#pragma unroll
    for (int kk = 0; kk < 2; ++kk)
      aLo[mi][kk] = LD((aoff + (unsigned)(mi * 2048)) ^ (unsigned)(kk << 6));
#pragma unroll
  for (int nj = 0; nj < 2; ++nj)
#pragma unroll
    for (int kk = 0; kk < 2; ++kk)
      b0v[nj][kk] = LD((boff + (unsigned)(nj * 2048)) ^ (unsigned)(kk << 6));

  for (int t = 0; t < nt; ++t) {
    const unsigned po = (unsigned)(t & 1) * 65536u;
    const unsigned pn = po ^ 65536u;

    // ---- P1: read b1(t); stage(t+1).B1; Q1 = aLo x b0 ----
#pragma unroll
    for (int nj = 0; nj < 2; ++nj)
#pragma unroll
      for (int kk = 0; kk < 2; ++kk)
        b1v[nj][kk] = LD((po + boff + (unsigned)((nj + 2) * 2048)) ^ (unsigned)(kk << 6));
    if (t + 1 < nt) stage(t + 1, 1, 1);
    PRIO(1);
#pragma unroll
    for (int kk = 0; kk < 2; ++kk)
#pragma unroll
      for (int mi = 0; mi < 4; ++mi)
#pragma unroll
        for (int nj = 0; nj < 2; ++nj)
          acc[mi][nj] = MFMA16(aLo[mi][kk], b0v[nj][kk], acc[mi][nj]);
    PRIO(0);

    // ---- P2: read aHi(t); stage(t+1).A1; Q2 = aLo x b1; BARRIER-A ----
#pragma unroll
    for (int mi = 0; mi < 4; ++mi)
#pragma unroll
      for (int kk = 0; kk < 2; ++kk)
        aHi[mi][kk] = LD((po + aoff + (unsigned)((mi + 4) * 2048)) ^ (unsigned)(kk << 6));
    if (t + 1 < nt) stage(t + 1, 1, 0);
    PRIO(1);
#pragma unroll
    for (int kk = 0; kk < 2; ++kk)
#pragma unroll
      for (int mi = 0; mi < 4; ++mi)
#pragma unroll
        for (int nj = 0; nj < 2; ++nj)
          acc[mi][nj + 2] = MFMA16(aLo[mi][kk], b1v[nj][kk], acc[mi][nj + 2]);
    PRIO(0);
    BAR();
    MEMFENCE();

    // ---- P3: Q3 = aHi x b0; stage(t+2).B0; publish t+1; BARRIER-B ----
    PRIO(1);
#pragma unroll
    for (int kk = 0; kk < 2; ++kk)
#pragma unroll
      for (int mi = 0; mi < 4; ++mi)
#pragma unroll
        for (int nj = 0; nj < 2; ++nj)
          acc[mi + 4][nj] = MFMA16(aHi[mi][kk], b0v[nj][kk], acc[mi + 4][nj]);
    PRIO(0);
    if (t + 2 < nt) stage(t + 2, 0, 1);
    if (t + 1 < nt) {
      if (t + 2 < nt) asm volatile("s_waitcnt vmcnt(2)");
      else            asm volatile("s_waitcnt vmcnt(0)");
      BAR();
      MEMFENCE();
    }

    // ---- P4: read aLo,b0(t+1); Q4 = aHi x b1; stage(t+2).A0 ----
    if (t + 1 < nt) {
#pragma unroll
      for (int mi = 0; mi < 4; ++mi)
#pragma unroll
        for (int kk = 0; kk < 2; ++kk)
          aLo[mi][kk] = LD((pn + aoff + (unsigned)(mi * 2048)) ^ (unsigned)(kk << 6));
#pragma unroll
      for (int nj = 0; nj < 2; ++nj)
#pragma unroll
        for (int kk = 0; kk < 2; ++kk)
          b0v[nj][kk] = LD((pn + boff + (unsigned)(nj * 2048)) ^ (unsigned)(kk << 6));
    }
    PRIO(1);
#pragma unroll
    for (int kk = 0; kk < 2; ++kk)
#pragma unroll
      for (int mi = 0; mi < 4; ++mi)
#pragma unroll
        for (int nj = 0; nj < 2; ++nj)
          acc[mi + 4][nj + 2] = MFMA16(aHi[mi][kk], b1v[nj][kk], acc[mi + 4][nj + 2]);
    PRIO(0);
    if (t + 2 < nt) stage(t + 2, 0, 0);
  }

  float biasv[4];
#pragma unroll
  for (int nj = 0; nj < 4; ++nj)
    biasv[nj] = bias[bn + wn * 64 + nj * 16 + ln15];

#pragma unroll
  for (int mi = 0; mi < 8; ++mi) {
    int row0 = bm + wm * 128 + mi * 16 + (lane >> 4) * 4;
#pragma unroll
    for (int nj = 0; nj < 4; ++nj) {
      int col = bn + wn * 64 + nj * 16 + ln15;
#pragma unroll
      for (int r = 0; r < 4; ++r) {
        float v = acc[mi][nj][r] + biasv[nj];
        v = v > 0.f ? v : 0.f;
        size_t idx = (size_t)(row0 + r) * N + col;
        Cb[idx] = __float2bfloat16(v);
        if (Cf) Cf[idx] = v;
      }
    }
  }
}

// ---------------------------------------------------------------------------
// gemm_128: 128x256, BK=64, 8 waves 2x4 (wave tile 64x64), R6 2-barrier
// schedule (asm reads). Loads/tile = 6; publish vmcnt(2); prologue vmcnt(3).
// ---------------------------------------------------------------------------
__global__ __launch_bounds__(512, 2) void gemm_128(
    const __hip_bfloat16* __restrict__ A,
    const __hip_bfloat16* __restrict__ Bt,
    const float* __restrict__ bias,
    __hip_bfloat16* __restrict__ Cb,
    float* __restrict__ Cf,
    int N, int K, int nbx) {
  __shared__ char lds[98304];

  const int tid  = threadIdx.x;
  const int lane = tid & 63;
  const int wid  = tid >> 6;
  const int wm   = wid >> 2;
  const int wn   = wid & 3;

  const int nwg = gridDim.x;
  const int cpx = nwg >> 3;
  const int id  = blockIdx.x;
  const int swz = (id & 7) * cpx + (id >> 3);
  const int bm  = (swz / nbx) * 128;
  const int bn  = (swz % nbx) * 256;

  const int ln15 = lane & 15;
  const unsigned cswz = (unsigned)((((lane >> 4) ^ (lane & 7)) << 4));

  const unsigned lbase = lds_u32(lds);
  const unsigned arow0 = lbase + (unsigned)(wm * 64 + ln15) * 128u + cswz;
  const unsigned brow0 = lbase + 16384u + (unsigned)(wn * 64 + ln15) * 128u + cswz;

  const int nt = K >> 6;

  const int swc = (tid & 7) ^ ((tid >> 3) & 7);
  const __hip_bfloat16* baseA = A  + (size_t)(bm + (tid >> 3)) * K + swc * 8;
  const __hip_bfloat16* baseB = Bt + (size_t)(bn + (tid >> 3)) * K + swc * 8;
  const unsigned ldst0 = (unsigned)(tid * 16);

  auto stageA = [&](int kt, int half) {
    char* dst = lds + ((kt & 1) * 49152) + half * 8192;
    gload16(baseA + (size_t)((half * 64) * K + kt * 64), dst + ldst0);
  };
  auto stageB = [&](int kt, int half) {
    char* dst = lds + ((kt & 1) * 49152) + 16384 + half * 16384;
#pragma unroll
    for (int q = 0; q < 2; ++q) {
      gload16(baseB + (size_t)((half * 128 + q * 64) * K + kt * 64),
              dst + q * 8192 + ldst0);
    }
  };

  f32x4 acc[4][4] = {};
  short8 aLo[2][2], aHi[2][2], b0v[2][2], b1v[2][2];

  // prologue
  stageB(0, 0); stageA(0, 0); stageB(0, 1); stageA(0, 1);
  if (nt > 1) {
    stageB(1, 0); stageA(1, 0);
    asm volatile("s_waitcnt vmcnt(3)");
  } else {
    asm volatile("s_waitcnt vmcnt(0)");
  }
  BAR();
#pragma unroll
  for (int mi = 0; mi < 2; ++mi) {
    unsigned ad = arow0 + (unsigned)(mi * 2048);
    aLo[mi][0] = dsr(ad); aLo[mi][1] = dsr(ad ^ 64u);
  }

  for (int t = 0; t < nt; ++t) {
    const unsigned po = (unsigned)(t & 1) * 49152u;
    const unsigned pn = po ^ 49152u;

    // ---- P1 ----
    asm volatile("s_waitcnt lgkmcnt(0)");
    SB0();
#pragma unroll
    for (int nj = 0; nj < 2; ++nj) b0v[nj][0] = dsr(brow0 + po + (unsigned)(nj * 2048));
#pragma unroll
    for (int nj = 0; nj < 2; ++nj) b0v[nj][1] = dsr((brow0 + po + (unsigned)(nj * 2048)) ^ 64u);
#pragma unroll
    for (int nj = 0; nj < 2; ++nj) b1v[nj][0] = dsr(brow0 + po + (unsigned)((nj + 2) * 2048));
#pragma unroll
    for (int nj = 0; nj < 2; ++nj) b1v[nj][1] = dsr((brow0 + po + (unsigned)((nj + 2) * 2048)) ^ 64u);
    if (t + 1 < nt) stageB(t + 1, 1);
    asm volatile("s_waitcnt lgkmcnt(6)");
    SB0();
    PRIO(1);
#pragma unroll
    for (int mi = 0; mi < 2; ++mi)
#pragma unroll
      for (int nj = 0; nj < 2; ++nj)
        acc[mi][nj] = MFMA16(aLo[mi][0], b0v[nj][0], acc[mi][nj]);
    asm volatile("s_waitcnt lgkmcnt(4)");
    SB0();
#pragma unroll
    for (int mi = 0; mi < 2; ++mi)
#pragma unroll
      for (int nj = 0; nj < 2; ++nj)
        acc[mi][nj] = MFMA16(aLo[mi][1], b0v[nj][1], acc[mi][nj]);
    PRIO(0);

    // ---- P2 ----
#pragma unroll
    for (int mi = 0; mi < 2; ++mi) {
      unsigned ad = arow0 + po + (unsigned)((mi + 2) * 2048);
      aHi[mi][0] = dsr(ad); aHi[mi][1] = dsr(ad ^ 64u);
    }
    if (t + 1 < nt) stageA(t + 1, 1);
    asm volatile("s_waitcnt lgkmcnt(4)");
    SB0();
    PRIO(1);
#pragma unroll
    for (int kk = 0; kk < 2; ++kk)
#pragma unroll
      for (int mi = 0; mi < 2; ++mi)
#pragma unroll
        for (int nj = 0; nj < 2; ++nj)
          acc[mi][nj + 2] = MFMA16(aLo[mi][kk], b1v[nj][kk], acc[mi][nj + 2]);
    PRIO(0);
    BAR();

    // ---- P3 ----
    asm volatile("s_waitcnt lgkmcnt(0)");
    SB0();
    PRIO(1);
#pragma unroll
    for (int kk = 0; kk < 2; ++kk)
#pragma unroll
      for (int mi = 0; mi < 2; ++mi)
#pragma unroll
        for (int nj = 0; nj < 2; ++nj)
          acc[mi + 2][nj] = MFMA16(aHi[mi][kk], b0v[nj][kk], acc[mi + 2][nj]);
    PRIO(0);
    if (t + 2 < nt) stageB(t + 2, 0);
    if (t + 2 < nt)      asm volatile("s_waitcnt vmcnt(2)");
    else if (t + 1 < nt) asm volatile("s_waitcnt vmcnt(0)");
    if (t + 1 < nt) BAR();

    // ---- P4 ----
    if (t + 1 < nt) {
#pragma unroll
      for (int mi = 0; mi < 2; ++mi) {
        unsigned ad = arow0 + pn + (unsigned)(mi * 2048);
        aLo[mi][0] = dsr(ad); aLo[mi][1] = dsr(ad ^ 64u);
      }
    }
    SB0();
    PRIO(1);
#pragma unroll
    for (int kk = 0; kk < 2; ++kk)
#pragma unroll
      for (int mi = 0; mi < 2; ++mi)
#pragma unroll
        for (int nj = 0; nj < 2; ++nj)
          acc[mi + 2][nj + 2] = MFMA16(aHi[mi][kk], b1v[nj][kk], acc[mi + 2][nj + 2]);
    PRIO(0);
    if (t + 2 < nt) stageA(t + 2, 0);
  }

  float biasv[4];
#pragma unroll
  for (int nj = 0; nj < 4; ++nj)
    biasv[nj] = bias[bn + wn * 64 + nj * 16 + ln15];

#pragma unroll
  for (int mi = 0; mi < 4; ++mi) {
    int row0 = bm + wm * 64 + mi * 16 + (lane >> 4) * 4;
#pragma unroll
    for (int nj = 0; nj < 4; ++nj) {
      int col = bn + wn * 64 + nj * 16 + ln15;
#pragma unroll
      for (int r = 0; r < 4; ++r) {
        float v = acc[mi][nj][r] + biasv[nj];
        v = v > 0.f ? v : 0.f;
        size_t idx = (size_t)(row0 + r) * N + col;
        Cb[idx] = __float2bfloat16(v);
        if (Cf) Cf[idx] = v;
      }
    }
  }
}

// ---------------------------------------------------------------------------
// m97-structure 128x128 GEMM (L5 only).
// ---------------------------------------------------------------------------
__global__ __launch_bounds__(256, 2) void gemm_bt(
    const __hip_bfloat16* __restrict__ A,
    const __hip_bfloat16* __restrict__ Bt,
    const float* __restrict__ bias,
    __hip_bfloat16* __restrict__ Cb,
    float* __restrict__ Cf,
    int N, int K) {
  __shared__ char lds[32768];

  const int tid  = threadIdx.x;
  const int lane = tid & 63;
  const int wid  = tid >> 6;
  const int wm   = wid >> 1;
  const int wn   = wid & 1;
  const int bm   = blockIdx.y * 128;
  const int bn   = blockIdx.x * 128;

  f32x4 acc[4][4] = {};

  const int srow = tid >> 3;
  const int sk   = (tid & 7) * 8;
  const int kTiles = K >> 6;

  for (int kt = 0; kt < kTiles; ++kt) {
    __syncthreads();
    const __hip_bfloat16* ga = A  + (size_t)(bm + srow) * K + kt * 64 + sk;
    const __hip_bfloat16* gb = Bt + (size_t)(bn + srow) * K + kt * 64 + sk;
#pragma unroll
    for (int p = 0; p < 4; ++p) {
      gload16(ga + (size_t)(p * 32) * K, &lds[p * 4096 + wid * 1024]);
      gload16(gb + (size_t)(p * 32) * K, &lds[16384 + p * 4096 + wid * 1024]);
    }
    __syncthreads();

#pragma unroll
    for (int kk = 0; kk < 2; ++kk) {
      short8 avec[4], bvec[4];
#pragma unroll
      for (int i = 0; i < 4; ++i) {
        int row = wm * 64 + i * 16 + (lane & 15);
        avec[i] = *(const short8*)&lds[row * 128 + kk * 64 + (lane >> 4) * 16];
      }
#pragma unroll
      for (int j = 0; j < 4; ++j) {
        int row = wn * 64 + j * 16 + (lane & 15);
        bvec[j] = *(const short8*)&lds[16384 + row * 128 + kk * 64 + (lane >> 4) * 16];
      }
#pragma unroll
      for (int i = 0; i < 4; ++i)
#pragma unroll
        for (int j = 0; j < 4; ++j)
          acc[i][j] = MFMA16(avec[i], bvec[j], acc[i][j]);
    }
  }

  float biasv[4];
#pragma unroll
  for (int j = 0; j < 4; ++j)
    biasv[j] = bias[bn + wn * 64 + j * 16 + (lane & 15)];

#pragma unroll
  for (int i = 0; i < 4; ++i) {
    int row0 = bm + wm * 64 + i * 16 + (lane >> 4) * 4;
#pragma unroll
    for (int j = 0; j < 4; ++j) {
      int col = bn + wn * 64 + j * 16 + (lane & 15);
#pragma unroll
      for (int r = 0; r < 4; ++r) {
        float v = acc[i][j][r] + biasv[j];
        v = v > 0.f ? v : 0.f;
        size_t idx = (size_t)(row0 + r) * N + col;
        Cb[idx] = __float2bfloat16(v);
        if (Cf) Cf[idx] = v;
      }
    }
  }
}

// ---------------------------------------------------------------------------
// Head: out[r] = sigmoid( sum(wide[r,:]) + dot(D[r,:], Wh[dom[r],:]) + bh[dom[r]] )
// ---------------------------------------------------------------------------
__global__ __launch_bounds__(256) void head_kernel(
    const float* __restrict__ wide,
    const __hip_bfloat16* __restrict__ D,
    const int* __restrict__ dom,
    const float* __restrict__ Wh,
    const float* __restrict__ bh,
    float* __restrict__ out, int B) {
  const int wid  = threadIdx.x >> 6;
  const int lane = threadIdx.x & 63;
  const int row  = blockIdx.x * 4 + wid;
  if (row >= B) return;
  const int dm = dom[row];

  f32x4 wv = ((const f32x4*)(wide + (size_t)row * 256))[lane];
  float tot = wv[0] + wv[1] + wv[2] + wv[3];

  const unsigned short* drow = (const unsigned short*)(D + (size_t)row * 256);
  ushort4 dv = ((const ushort4*)drow)[lane];
  f32x4 hv = ((const f32x4*)(Wh + (size_t)dm * 256))[lane];
  tot += bf_bits2f(dv.x) * hv[0] + bf_bits2f(dv.y) * hv[1] +
         bf_bits2f(dv.z) * hv[2] + bf_bits2f(dv.w) * hv[3];

#pragma unroll
  for (int off = 32; off > 0; off >>= 1) tot += __shfl_xor(tot, off);

  if (lane == 0) {
    float x = tot + bh[dm];
    out[row] = 1.f / (1.f + __expf(-x));
  }
}

// ---------------------------------------------------------------------------
extern "C" void kernel_launch(void* const* d_in, const int* in_sizes, int n_in,
                              void* d_out, int out_size, void* d_ws, size_t ws_size,
                              hipStream_t stream) {
  const float* wide = (const float*)d_in[0];
  const float* deep = (const float*)d_in[1];
  const int*   dom  = (const int*)d_in[2];
  const float* W1  = (const float*)d_in[3];
  const float* b1  = (const float*)d_in[4];
  const float* W2  = (const float*)d_in[5];
  const float* b2  = (const float*)d_in[6];
  const float* W3  = (const float*)d_in[7];
  const float* b3  = (const float*)d_in[8];
  const float* Wd1 = (const float*)d_in[9];
  const float* bd1 = (const float*)d_in[10];
  const float* Wd2 = (const float*)d_in[11];
  const float* bd2 = (const float*)d_in[12];
  const float* Wh  = (const float*)d_in[13];
  const float* bh  = (const float*)d_in[14];
  float* out = (float*)d_out;

  const int B = 16384;
  char* ws = (char*)d_ws;
  __hip_bfloat16* buf0 = (__hip_bfloat16*)ws;
  __hip_bfloat16* buf1 = (__hip_bfloat16*)(ws + 33554432ull);
  __hip_bfloat16* W1t  = (__hip_bfloat16*)(ws + 100663296ull);
  __hip_bfloat16* W2t  = W1t + 2048 * 1024;
  __hip_bfloat16* W3t  = W2t + 1024 * 2048;
  __hip_bfloat16* Wd1t = W3t + 512 * 1024;
  __hip_bfloat16* Wd2t = Wd1t + 512 * 512;

  transpose_convert<<<dim3(2048 / 64, 1024 / 64), 256, 0, stream>>>(W1, W1t, 1024, 2048);
  transpose_convert<<<dim3(1024 / 64, 2048 / 64), 256, 0, stream>>>(W2, W2t, 2048, 1024);
  transpose_convert<<<dim3(512 / 64, 1024 / 64), 256, 0, stream>>>(W3, W3t, 1024, 512);
  transpose_convert<<<dim3(512 / 64, 512 / 64), 256, 0, stream>>>(Wd1, Wd1t, 512, 512);
  transpose_convert<<<dim3(256 / 64, 512 / 64), 256, 0, stream>>>(Wd2, Wd2t, 512, 256);

  {
    int n8 = B * 1024 / 8;
    f32_to_bf16<<<(n8 + 255) / 256, 256, 0, stream>>>(deep, (unsigned short*)buf0, n8);
  }

  float* shared_out = out + B;
  float* d_out_f    = out + B + (size_t)B * 512;

  // L1: [B,1024]x[1024,2048] -> H1 (buf1)
  gemm_2c<<<dim3((2048 / 256) * (B / 256)), 512, 0, stream>>>(
      buf0, W1t, b1, buf1, nullptr, 2048, 1024, 2048 / 256);
  // L2: [B,2048]x[2048,1024] -> H2 (buf0)
  gemm_2c<<<dim3((1024 / 256) * (B / 256)), 512, 0, stream>>>(
      buf1, W2t, b2, buf0, nullptr, 1024, 2048, 1024 / 256);
  // L3: [B,1024]x[1024,512] -> S (buf1 bf16 + fp32 out)
  gemm_128<<<dim3((B / 128) * (512 / 256)), 512, 0, stream>>>(
      buf0, W3t, b3, buf1, shared_out, 512, 1024, 512 / 256);
  // L4: [B,512]x[512,512] -> T1 (buf0)
  gemm_128<<<dim3((B / 128) * (512 / 256)), 512, 0, stream>>>(
      buf1, Wd1t, bd1, buf0, nullptr, 512, 512, 512 / 256);
  // L5: [B,512]x[512,256] -> D (buf1 bf16 + fp32 out)
  gemm_bt<<<dim3(256 / 128, B / 128), 256, 0, stream>>>(buf0, Wd2t, bd2, buf1, d_out_f, 256, 512);

  head_kernel<<<B / 4, 256, 0, stream>>>(wide, buf1, dom, Wh, bh, out, B);
}